// Round 1
// baseline (11330.722 us; speedup 1.0000x reference)
//
#include <hip/hip_runtime.h>
#include <hip/hip_bf16.h>
#include <math.h>

#define B_  128
#define S_  512
#define H_  768
#define NH_ 8
#define T_  20
#define HD_ 96

typedef unsigned short u16;
typedef unsigned int   u32;

__device__ __forceinline__ float wsum(float v){
  #pragma unroll
  for(int o=32;o;o>>=1) v += __shfl_xor(v,o);
  return v;
}
__device__ __forceinline__ float wmaxr(float v){
  #pragma unroll
  for(int o=32;o;o>>=1) v = fmaxf(v, __shfl_xor(v,o));
  return v;
}
__device__ __forceinline__ u16 f2bf(float f){
  u32 u = __float_as_uint(f);
  u32 r = (u + 0x7fffu + ((u>>16)&1u)) >> 16;
  return (u16)r;
}
__device__ __forceinline__ float bf2f(u32 bits){
  return __uint_as_float(bits<<16);
}

// ---------------- pooling: text_pooled / image_pooled (B,H) ----------------
__global__ void k_pool(const float* __restrict__ ehs, const int* __restrict__ sm,
                       const int* __restrict__ im, float* __restrict__ pt, float* __restrict__ pi){
  int b = blockIdx.x, tid = threadIdx.x;
  __shared__ float smf[S_], imf[S_];
  for(int s=tid;s<S_;s+=256){ smf[s]=(float)sm[b*S_+s]; imf[s]=(float)im[b*S_+s]; }
  __syncthreads();
  float tl=0.f, il=0.f;
  for(int s=0;s<S_;s++){ tl+=smf[s]; il+=imf[s]; }
  tl = fmaxf(tl, 1e-9f); il = fmaxf(il, 1e-9f);
  for(int h=tid;h<H_;h+=256){
    const float* base = ehs + (size_t)b*S_*H_ + h;
    float ts=0.f, is=0.f;
    for(int s=0;s<S_;s++){
      float a = base[(size_t)s*H_];
      ts += a*smf[s]*smf[s];
      is += a*imf[s]*imf[s];
    }
    pt[b*H_+h] = ts/tl;
    pi[b*H_+h] = is/il;
  }
}

// ------------- seed projection: leaky_relu(x@W1^T+b1) -> LN -> @W2^T+b2 -------------
__global__ void k_proj(const float* __restrict__ x_all, const float* __restrict__ W1,
                       const float* __restrict__ b1, const float* __restrict__ g,
                       const float* __restrict__ be, const float* __restrict__ W2,
                       const float* __restrict__ b2, float* __restrict__ out){
  int b = blockIdx.x, tid = threadIdx.x, lane = tid&63, w = tid>>6;
  __shared__ float sx[H_], sh[H_];
  __shared__ float red[4];
  for(int j=tid;j<H_;j+=256) sx[j] = x_all[b*H_+j];
  __syncthreads();
  for(int j=w;j<H_;j+=4){
    const float* row = W1 + (size_t)j*H_;
    float p=0.f;
    for(int k=lane;k<H_;k+=64) p += sx[k]*row[k];
    p = wsum(p);
    if(lane==0){ float v = p + b1[j]; sh[j] = (v>=0.f)? v : 0.01f*v; }
  }
  __syncthreads();
  float ps=0.f; for(int j=tid;j<H_;j+=256) ps+=sh[j];
  ps = wsum(ps); if(lane==0) red[w]=ps;
  __syncthreads();
  float mean = (red[0]+red[1]+red[2]+red[3])/(float)H_;
  __syncthreads();
  float pv=0.f; for(int j=tid;j<H_;j+=256){ float d=sh[j]-mean; pv+=d*d; }
  pv = wsum(pv); if(lane==0) red[w]=pv;
  __syncthreads();
  float rstd = rsqrtf((red[0]+red[1]+red[2]+red[3])/(float)H_ + 1e-5f);
  __syncthreads();
  for(int j=tid;j<H_;j+=256) sx[j] = (sh[j]-mean)*rstd*g[j] + be[j];
  __syncthreads();
  for(int j=w;j<H_;j+=4){
    const float* row = W2 + (size_t)j*H_;
    float p=0.f;
    for(int k=lane;k<H_;k+=64) p += sx[k]*row[k];
    p = wsum(p);
    if(lane==0) out[b*H_+j] = p + b2[j];
  }
}

// ------------- query = alpha*seed_i + (1-alpha)*seed_t + sinusoid PE -------------
__global__ void k_query(const float* __restrict__ st, const float* __restrict__ si,
                        const float* __restrict__ rel, float* __restrict__ q){
  int bt = blockIdx.x; int b = bt/T_, t = bt%T_; int tid = threadIdx.x;
  float a = rel[b];
  const float c = 9.210340371976184f/(float)H_;  // ln(10000)/H
  for(int h=tid;h<H_;h+=256){
    float ang = (float)t * expf(-(float)(h & ~1) * c);
    float pe  = (h&1)? cosf(ang) : sinf(ang);
    q[(size_t)bt*H_+h] = a*si[b*H_+h] + (1.f-a)*st[b*H_+h] + pe;
  }
}

// ------------- 768x768 transpose (for coalesced Wout access) -------------
__global__ void k_transpose768(const float* __restrict__ A, float* __restrict__ At){
  __shared__ float tile[32][33];
  int bx = blockIdx.x % 24, by = blockIdx.x / 24;
  int tx = threadIdx.x & 31, ty = threadIdx.x >> 5;   // 32 x 8
  int c0 = bx*32, r0 = by*32;
  for(int rr=ty; rr<32; rr+=8) tile[rr][tx] = A[(size_t)(r0+rr)*H_ + c0+tx];
  __syncthreads();
  for(int rr=ty; rr<32; rr+=8) At[(size_t)(c0+rr)*H_ + r0+tx] = tile[tx][rr];
}

// ------------- fused attention per (b, mha, head) -------------
// scores[t,s] = (u_t . ehs_s)*mf_s + bias_t, u_t = Wk_h^T qh_t ;
// ctx[t,:] = sum_s p*mf*ehs ; out += (ctx@Wv_h^T + bv) @ WoutT[h-cols]
__global__ __launch_bounds__(256,2) void k_attn(
    const float* __restrict__ ehs, const float* __restrict__ query,
    const float* __restrict__ taWin, const float* __restrict__ taBin,
    const float* __restrict__ iaWin, const float* __restrict__ iaBin,
    const float* __restrict__ WoTt, const float* __restrict__ WoTi,
    const int* __restrict__ smask, const int* __restrict__ imask,
    float* __restrict__ out_t, float* __restrict__ out_i)
{
  int gb = blockIdx.x;
  int b = gb >> 4, r = gb & 15, mha = r >> 3, h = r & 7;
  const float* Win = mha? iaWin : taWin;
  const float* bIn = mha? iaBin : taBin;
  const float* WoT = mha? WoTi  : WoTt;
  const int*   msk = mha? imask : smask;
  float*      outp = mha? out_i : out_t;
  const float* Wq = Win;
  const float* Wk = Win + (size_t)H_*H_;
  const float* Wv = Win + (size_t)2*H_*H_;
  const float* bq = bIn, *bk = bIn+H_, *bv = bIn+2*H_;
  const int hd0 = h*HD_;

  int tid = threadIdx.x, lane = tid&63, w = tid>>6;
  const int t0 = w*5;  // each wave owns 5 query rows

  __shared__ float sqh[T_*HD_];       // qh, later reused as vtmp
  __shared__ float sbias[T_];
  __shared__ u16   sp[T_*S_];         // probs (bf16, post *mf/rowsum)
  __shared__ float smf[S_];
  __shared__ __align__(16) float region[7728]; // union: {suk+Et} | E2 | ctx(bf16)
  float* suk = region;            // [20][8]
  float* sEt = region + 160;      // [8][516]  (transposed ehs k-chunk)
  float* sE2 = region;            // [8][772]
  u16*  sctx = (u16*)region;      // [20][772]

  // ---- qh = query @ Wq_h^T + bq (wave-dot) ----
  const float* qrow = query + (size_t)b*T_*H_;
  for(int o=w; o<T_*HD_; o+=4){
    int t = o/HD_, d = o%HD_;
    const float* wr = Wq + (size_t)(hd0+d)*H_;
    const float* xr = qrow + (size_t)t*H_;
    float p=0.f;
    for(int k=lane;k<H_;k+=64) p += xr[k]*wr[k];
    p = wsum(p);
    if(lane==0) sqh[o] = p + bq[hd0+d];
  }
  __syncthreads();
  if(tid<T_){
    float p=0.f;
    for(int d=0;d<HD_;d++) p += sqh[tid*HD_+d]*bk[hd0+d];
    sbias[tid]=p;
  }
  for(int s=tid;s<S_;s+=256) smf[s] = (float)msk[b*S_+s];
  __syncthreads();

  // ---- phase 1: scores (T x S), K-chunked by 8 ----
  float acc[5][8];
  #pragma unroll
  for(int a=0;a<5;a++)
    #pragma unroll
    for(int j=0;j<8;j++) acc[a][j]=0.f;

  for(int k0=0;k0<H_;k0+=8){
    if(tid < 160){                       // u chunk: [t][kk]
      int t = tid>>3, kk = tid&7;
      const float* wc = Wk + (size_t)hd0*H_ + k0 + kk;
      float p=0.f;
      #pragma unroll
      for(int d=0;d<HD_;d++) p += sqh[t*HD_+d]*wc[(size_t)d*H_];
      suk[tid]=p;
    }
    {                                    // ehs^T chunk: sEt[kk][s]
      int half = tid&1, sb = tid>>1;
      #pragma unroll
      for(int rep=0;rep<4;rep++){
        int s = sb + 128*rep;
        float4 v = *(const float4*)(ehs + (size_t)b*S_*H_ + (size_t)s*H_ + k0 + 4*half);
        sEt[(4*half+0)*516 + s] = v.x;
        sEt[(4*half+1)*516 + s] = v.y;
        sEt[(4*half+2)*516 + s] = v.z;
        sEt[(4*half+3)*516 + s] = v.w;
      }
    }
    __syncthreads();
    #pragma unroll
    for(int kk=0;kk<8;kk++){
      float uu[5];
      #pragma unroll
      for(int tt=0;tt<5;tt++) uu[tt] = suk[(t0+tt)*8+kk];
      #pragma unroll
      for(int jj=0;jj<4;jj++){
        float2 e = *(const float2*)&sEt[kk*516 + 2*lane + 128*jj];
        #pragma unroll
        for(int tt=0;tt<5;tt++){
          acc[tt][2*jj]   += uu[tt]*e.x;
          acc[tt][2*jj+1] += uu[tt]*e.y;
        }
      }
    }
    __syncthreads();
  }

  // ---- softmax (each wave holds full rows for its 5 t's) ----
  const float rscale = 0.10206207261596577f;   // 1/sqrt(96)
  #pragma unroll
  for(int tt=0;tt<5;tt++){
    int t = t0+tt;
    float bias = sbias[t];
    float sc[8]; float mx = -3.4e38f;
    #pragma unroll
    for(int j=0;j<8;j++){
      int s = 2*lane + (j&1) + 128*(j>>1);
      float mf = smf[s];
      float v = (acc[tt][j]*mf + bias)*rscale;
      if(mf==0.f) v = -1e9f;
      sc[j]=v; mx = fmaxf(mx,v);
    }
    mx = wmaxr(mx);
    float sum=0.f;
    #pragma unroll
    for(int j=0;j<8;j++){ float e = expf(sc[j]-mx); sc[j]=e; sum+=e; }
    sum = wsum(sum);
    float inv = 1.f/sum;
    #pragma unroll
    for(int j=0;j<8;j++){
      int s = 2*lane + (j&1) + 128*(j>>1);
      sp[t*S_+s] = f2bf(sc[j]*inv*smf[s]);
    }
  }
  __syncthreads();

  // ---- phase 2: ctx (T x H) = P @ ehs, s-chunked by 8 ----
  float c2[5][12];
  #pragma unroll
  for(int a=0;a<5;a++)
    #pragma unroll
    for(int j=0;j<12;j++) c2[a][j]=0.f;

  for(int s0=0;s0<S_;s0+=8){
    for(int e=tid; e<8*192; e+=256){
      int rr = e/192, cq = e%192;
      float4 v = *(const float4*)(ehs + (size_t)b*S_*H_ + (size_t)(s0+rr)*H_ + 4*cq);
      *(float4*)&sE2[rr*772 + 4*cq] = v;
    }
    __syncthreads();
    #pragma unroll
    for(int rr=0;rr<8;rr++){
      int s = s0+rr;
      float pp[5];
      #pragma unroll
      for(int tt=0;tt<5;tt++) pp[tt] = bf2f(sp[(t0+tt)*S_ + s]);
      #pragma unroll
      for(int jj=0;jj<6;jj++){
        float2 e = *(const float2*)&sE2[rr*772 + 2*lane + 128*jj];
        #pragma unroll
        for(int tt=0;tt<5;tt++){
          c2[tt][2*jj]   += pp[tt]*e.x;
          c2[tt][2*jj+1] += pp[tt]*e.y;
        }
      }
    }
    __syncthreads();
  }

  // ---- phase 3: ctx -> LDS (bf16), then vtmp = ctx@Wv_h^T + bv ----
  #pragma unroll
  for(int tt=0;tt<5;tt++)
    #pragma unroll
    for(int jj=0;jj<6;jj++){
      int cc = 2*lane + 128*jj;
      u32 packed = (u32)f2bf(c2[tt][2*jj]) | ((u32)f2bf(c2[tt][2*jj+1])<<16);
      *(u32*)&sctx[(t0+tt)*772 + cc] = packed;
    }
  __syncthreads();
  for(int o=w; o<T_*HD_; o+=4){
    int t = o/HD_, d = o%HD_;
    const float* wr = Wv + (size_t)(hd0+d)*H_;
    const u16*   cr = sctx + t*772;
    float p=0.f;
    #pragma unroll
    for(int i=0;i<6;i++){
      int cc = 2*lane + 128*i;
      u32 u2 = *(const u32*)&cr[cc];
      float2 wv = *(const float2*)&wr[cc];
      p += bf2f(u2&0xffffu)*wv.x + bf2f(u2>>16)*wv.y;
    }
    p = wsum(p);
    if(lane==0) sqh[o] = p + bv[hd0+d];    // vtmp reuses sqh
  }
  __syncthreads();

  // ---- phase 4: out[b,t,:] += vtmp @ Wout[:, h-cols]^T (via pre-transposed WoT) ----
  float* op = outp + (size_t)b*T_*H_;
  for(int rep=0;rep<3;rep++){
    int j = tid + 256*rep;
    float oacc[T_];
    #pragma unroll
    for(int t=0;t<T_;t++) oacc[t]=0.f;
    for(int d=0;d<HD_;d++){
      float wv = WoT[(size_t)(hd0+d)*H_ + j];
      #pragma unroll
      for(int t=0;t<T_;t++) oacc[t] += sqh[t*HD_+d]*wv;
    }
    #pragma unroll
    for(int t=0;t<T_;t++) atomicAdd(op + (size_t)t*H_ + j, oacc[t]);
  }
}

// ------------- combine + laW GEMV + LN + relu -> cap (d_out) -------------
__global__ void k_cap(const float* __restrict__ out_t, const float* __restrict__ out_i,
                      const float* __restrict__ taBout, const float* __restrict__ iaBout,
                      const float* __restrict__ rel, const float* __restrict__ laW,
                      const float* __restrict__ laB, const float* __restrict__ laG,
                      const float* __restrict__ laBe, float* __restrict__ cap){
  int bt = blockIdx.x; int b = bt/T_;
  int tid = threadIdx.x, lane = tid&63, w = tid>>6;
  float beta = rel[b];
  __shared__ float sx[H_], sy[H_];
  __shared__ float red[4];
  for(int j=tid;j<H_;j+=256){
    float vt = out_t[(size_t)bt*H_+j] + taBout[j];
    float vi = out_i[(size_t)bt*H_+j] + iaBout[j];
    sx[j] = beta*vi + (1.f-beta)*vt;
  }
  __syncthreads();
  for(int j=w;j<H_;j+=4){
    const float* row = laW + (size_t)j*H_;
    float p=0.f;
    for(int k=lane;k<H_;k+=64) p += sx[k]*row[k];
    p = wsum(p);
    if(lane==0) sy[j] = p + laB[j];
  }
  __syncthreads();
  float ps=0.f; for(int j=tid;j<H_;j+=256) ps+=sy[j];
  ps=wsum(ps); if(lane==0) red[w]=ps;
  __syncthreads();
  float mean=(red[0]+red[1]+red[2]+red[3])/(float)H_;
  __syncthreads();
  float pv=0.f; for(int j=tid;j<H_;j+=256){ float d=sy[j]-mean; pv+=d*d; }
  pv=wsum(pv); if(lane==0) red[w]=pv;
  __syncthreads();
  float rstd=rsqrtf((red[0]+red[1]+red[2]+red[3])/(float)H_ + 1e-5f);
  for(int j=tid;j<H_;j+=256){
    float v=(sy[j]-mean)*rstd*laG[j]+laBe[j];
    cap[(size_t)bt*H_+j] = (v>0.f)? v : 0.f;
  }
}

__global__ void k_mean(const float* __restrict__ cap, float* __restrict__ m){
  int b=blockIdx.x, tid=threadIdx.x;
  for(int hh=tid;hh<H_;hh+=256){
    float s=0.f;
    for(int t=0;t<T_;t++) s += cap[((size_t)b*T_+t)*H_+hh];
    m[b*H_+hh] = s*(1.f/(float)T_);
  }
}

__global__ void k_quality(const float* __restrict__ m, const float* __restrict__ qW1,
                          const float* __restrict__ qB1, const float* __restrict__ qG,
                          const float* __restrict__ qBe, const float* __restrict__ qW2,
                          const float* __restrict__ qB2, float* __restrict__ outq){
  int b=blockIdx.x, tid=threadIdx.x, lane=tid&63, w=tid>>6;
  const int H2 = H_/2;
  __shared__ float sx[H_], sh[H_/2];
  __shared__ float red[4];
  for(int j=tid;j<H_;j+=256) sx[j]=m[b*H_+j];
  __syncthreads();
  for(int j=w;j<H2;j+=4){
    const float* row = qW1 + (size_t)j*H_;
    float p=0.f;
    for(int k=lane;k<H_;k+=64) p += sx[k]*row[k];
    p=wsum(p);
    if(lane==0) sh[j]=p+qB1[j];
  }
  __syncthreads();
  float ps=0.f; for(int j=tid;j<H2;j+=256) ps+=sh[j];
  ps=wsum(ps); if(lane==0) red[w]=ps;
  __syncthreads();
  float mean=(red[0]+red[1]+red[2]+red[3])/(float)H2;
  __syncthreads();
  float pv=0.f; for(int j=tid;j<H2;j+=256){ float d=sh[j]-mean; pv+=d*d; }
  pv=wsum(pv); if(lane==0) red[w]=pv;
  __syncthreads();
  float rstd=rsqrtf((red[0]+red[1]+red[2]+red[3])/(float)H2 + 1e-5f);
  __syncthreads();
  float dot=0.f;
  for(int j=tid;j<H2;j+=256){
    float v=(sh[j]-mean)*rstd*qG[j]+qBe[j];
    v = (v>0.f)? v:0.f;
    dot += v*qW2[j];
  }
  dot=wsum(dot); if(lane==0) red[w]=dot;
  __syncthreads();
  if(tid==0){
    float z = red[0]+red[1]+red[2]+red[3]+qB2[0];
    outq[b] = 1.f/(1.f+expf(-z));
  }
}

extern "C" void kernel_launch(void* const* d_in, const int* in_sizes, int n_in,
                              void* d_out, int out_size, void* d_ws, size_t ws_size,
                              hipStream_t stream){
  const float* ehs    = (const float*)d_in[0];
  const float* rel    = (const float*)d_in[1];
  const float* tW1    = (const float*)d_in[3];
  const float* tb1    = (const float*)d_in[4];
  const float* tg     = (const float*)d_in[5];
  const float* tbe    = (const float*)d_in[6];
  const float* tW2    = (const float*)d_in[7];
  const float* tb2    = (const float*)d_in[8];
  const float* iW1    = (const float*)d_in[9];
  const float* ib1    = (const float*)d_in[10];
  const float* ig     = (const float*)d_in[11];
  const float* ibe    = (const float*)d_in[12];
  const float* iW2    = (const float*)d_in[13];
  const float* ib2    = (const float*)d_in[14];
  const float* taWin  = (const float*)d_in[15];
  const float* taBin  = (const float*)d_in[16];
  const float* taWout = (const float*)d_in[17];
  const float* taBout = (const float*)d_in[18];
  const float* iaWin  = (const float*)d_in[19];
  const float* iaBin  = (const float*)d_in[20];
  const float* iaWout = (const float*)d_in[21];
  const float* iaBout = (const float*)d_in[22];
  const float* laW    = (const float*)d_in[23];
  const float* laB    = (const float*)d_in[24];
  const float* laG    = (const float*)d_in[25];
  const float* laBe   = (const float*)d_in[26];
  const float* qW1    = (const float*)d_in[27];
  const float* qB1    = (const float*)d_in[28];
  const float* qG     = (const float*)d_in[29];
  const float* qBe    = (const float*)d_in[30];
  const float* qW2    = (const float*)d_in[31];
  const float* qB2    = (const float*)d_in[32];
  const int* smask    = (const int*)d_in[33];
  const int* imask    = (const int*)d_in[34];

  float* ws   = (float*)d_ws;
  float* pt   = ws;                       // B*H
  float* pi   = pt  + B_*H_;
  float* st   = pi  + B_*H_;
  float* si   = st  + B_*H_;
  float* query= si  + B_*H_;              // B*T*H
  float* out_t= query + (size_t)B_*T_*H_;
  float* out_i= out_t + (size_t)B_*T_*H_;
  float* mbuf = out_i + (size_t)B_*T_*H_; // B*H
  float* WoTt = mbuf + B_*H_;             // H*H
  float* WoTi = WoTt + (size_t)H_*H_;

  hipLaunchKernelGGL(k_pool,  dim3(B_),      dim3(256), 0, stream, ehs, smask, imask, pt, pi);
  hipLaunchKernelGGL(k_proj,  dim3(B_),      dim3(256), 0, stream, pt, tW1, tb1, tg, tbe, tW2, tb2, st);
  hipLaunchKernelGGL(k_proj,  dim3(B_),      dim3(256), 0, stream, pi, iW1, ib1, ig, ibe, iW2, ib2, si);
  hipLaunchKernelGGL(k_query, dim3(B_*T_),   dim3(256), 0, stream, st, si, rel, query);
  hipLaunchKernelGGL(k_transpose768, dim3(576), dim3(256), 0, stream, taWout, WoTt);
  hipLaunchKernelGGL(k_transpose768, dim3(576), dim3(256), 0, stream, iaWout, WoTi);
  hipMemsetAsync(out_t, 0, (size_t)2*B_*T_*H_*sizeof(float), stream);
  hipLaunchKernelGGL(k_attn,  dim3(B_*2*NH_), dim3(256), 0, stream,
                     ehs, query, taWin, taBin, iaWin, iaBin, WoTt, WoTi, smask, imask, out_t, out_i);
  float* cap = (float*)d_out;
  hipLaunchKernelGGL(k_cap,   dim3(B_*T_),   dim3(256), 0, stream,
                     out_t, out_i, taBout, iaBout, rel, laW, laB, laG, laBe, cap);
  hipLaunchKernelGGL(k_mean,  dim3(B_),      dim3(256), 0, stream, cap, mbuf);
  hipLaunchKernelGGL(k_quality, dim3(B_),    dim3(256), 0, stream,
                     mbuf, qW1, qB1, qG, qBe, qW2, qB2, cap + (size_t)B_*T_*H_);
}

// Round 2
// 4650.583 us; speedup vs baseline: 2.4364x; 2.4364x over previous
//
#include <hip/hip_runtime.h>
#include <hip/hip_bf16.h>
#include <math.h>

#define B_  128
#define S_  512
#define H_  768
#define NH_ 8
#define T_  20
#define HD_ 96

typedef unsigned short u16;
typedef unsigned int   u32;

typedef __attribute__((ext_vector_type(8))) short bhalf8;
typedef __attribute__((ext_vector_type(4))) float f32x4;

union U8 { bhalf8 s; u32 u[4]; };

__device__ __forceinline__ f32x4 mfma16(bhalf8 a, bhalf8 b, f32x4 c){
  return __builtin_amdgcn_mfma_f32_16x16x32_bf16(a, b, c, 0, 0, 0);
}
__device__ __forceinline__ u32 cvtpk(float lo, float hi){
  u32 r; asm volatile("v_cvt_pk_bf16_f32 %0, %1, %2" : "=v"(r) : "v"(lo), "v"(hi));
  return r;
}
__device__ __forceinline__ float wsum(float v){
  #pragma unroll
  for(int o=32;o;o>>=1) v += __shfl_xor(v,o);
  return v;
}
__device__ __forceinline__ float wmaxr(float v){
  #pragma unroll
  for(int o=32;o;o>>=1) v = fmaxf(v, __shfl_xor(v,o));
  return v;
}
__device__ __forceinline__ u16 f2bf(float f){
  u32 u = __float_as_uint(f);
  u32 r = (u + 0x7fffu + ((u>>16)&1u)) >> 16;
  return (u16)r;
}
__device__ __forceinline__ float bf2f(u32 bits){
  return __uint_as_float(bits<<16);
}

// ---------------- generic f32 -> bf16 (pairs) ----------------
__global__ void k_cvt(const float* __restrict__ src, u16* __restrict__ dst, int n2){
  int i = blockIdx.x*256 + threadIdx.x;
  if(i < n2){
    u32 r = cvtpk(src[2*i], src[2*i+1]);
    *(u32*)(dst + 2*i) = r;
  }
}

// ---------------- WkT[mha][n][k] = Wk[k][n] (bf16) ----------------
__global__ void k_wkt(const float* __restrict__ taWin, const float* __restrict__ iaWin,
                      u16* __restrict__ WkT){
  int blk = blockIdx.x; int mha = blk/576; int t = blk%576;
  const float* Wk = (mha? iaWin : taWin) + (size_t)H_*H_;
  int bx = t%24, by = t/24;
  __shared__ float tile[32][33];
  int tx = threadIdx.x & 31, ty = threadIdx.x >> 5;
  for(int rr=ty; rr<32; rr+=8) tile[rr][tx] = Wk[(size_t)(by*32+rr)*H_ + bx*32+tx];
  __syncthreads();
  u16* dst = WkT + (size_t)mha*H_*H_;
  for(int rr=ty; rr<32; rr+=8) dst[(size_t)(bx*32+rr)*H_ + by*32+tx] = f2bf(tile[tx][rr]);
}

// ---------------- pooling ----------------
__global__ void k_pool(const float* __restrict__ ehs, const int* __restrict__ sm,
                       const int* __restrict__ im, float* __restrict__ pt, float* __restrict__ pi){
  int blk = blockIdx.x; int b = blk/3; int c0 = (blk%3)*256;
  int tid = threadIdx.x;
  __shared__ float smf[S_], imf[S_];
  for(int s=tid;s<S_;s+=256){ smf[s]=(float)sm[b*S_+s]; imf[s]=(float)im[b*S_+s]; }
  __syncthreads();
  float tl=0.f, il=0.f;
  for(int s=0;s<S_;s++){ tl+=smf[s]; il+=imf[s]; }
  tl = fmaxf(tl, 1e-9f); il = fmaxf(il, 1e-9f);
  int col = c0 + tid;
  const float* base = ehs + (size_t)b*S_*H_ + col;
  float ts=0.f, is=0.f;
  for(int s=0;s<S_;s++){
    float a = base[(size_t)s*H_];
    ts += a*smf[s];
    is += a*imf[s];
  }
  pt[b*H_+col] = ts/tl;
  pi[b*H_+col] = is/il;
}

// ---------------- seed projection (unchanged, known-correct) ----------------
__global__ void k_proj(const float* __restrict__ x_all, const float* __restrict__ W1,
                       const float* __restrict__ b1, const float* __restrict__ g,
                       const float* __restrict__ be, const float* __restrict__ W2,
                       const float* __restrict__ b2, float* __restrict__ out){
  int b = blockIdx.x, tid = threadIdx.x, lane = tid&63, w = tid>>6;
  __shared__ float sx[H_], sh[H_];
  __shared__ float red[4];
  for(int j=tid;j<H_;j+=256) sx[j] = x_all[b*H_+j];
  __syncthreads();
  for(int j=w;j<H_;j+=4){
    const float* row = W1 + (size_t)j*H_;
    float p=0.f;
    for(int k=lane;k<H_;k+=64) p += sx[k]*row[k];
    p = wsum(p);
    if(lane==0){ float v = p + b1[j]; sh[j] = (v>=0.f)? v : 0.01f*v; }
  }
  __syncthreads();
  float ps=0.f; for(int j=tid;j<H_;j+=256) ps+=sh[j];
  ps = wsum(ps); if(lane==0) red[w]=ps;
  __syncthreads();
  float mean = (red[0]+red[1]+red[2]+red[3])/(float)H_;
  __syncthreads();
  float pv=0.f; for(int j=tid;j<H_;j+=256){ float d=sh[j]-mean; pv+=d*d; }
  pv = wsum(pv); if(lane==0) red[w]=pv;
  __syncthreads();
  float rstd = rsqrtf((red[0]+red[1]+red[2]+red[3])/(float)H_ + 1e-5f);
  __syncthreads();
  for(int j=tid;j<H_;j+=256) sx[j] = (sh[j]-mean)*rstd*g[j] + be[j];
  __syncthreads();
  for(int j=w;j<H_;j+=4){
    const float* row = W2 + (size_t)j*H_;
    float p=0.f;
    for(int k=lane;k<H_;k+=64) p += sx[k]*row[k];
    p = wsum(p);
    if(lane==0) out[b*H_+j] = p + b2[j];
  }
}

// ---------------- query (padded to 32 rows, bf16) ----------------
__global__ void k_query(const float* __restrict__ st, const float* __restrict__ si,
                        const float* __restrict__ rel, u16* __restrict__ query_b){
  int b = blockIdx.x; int tid = threadIdx.x;
  float a = rel[b];
  const float c = 9.210340371976184f/(float)H_;  // ln(10000)/H
  for(int t=0;t<32;t++){
    for(int h=tid;h<H_;h+=256){
      float val = 0.f;
      if(t < T_){
        float ang = (float)t * __expf(-(float)(h & ~1) * c);
        float pe  = (h&1)? __cosf(ang) : __sinf(ang);
        val = a*si[b*H_+h] + (1.f-a)*st[b*H_+h] + pe;
      }
      query_b[(size_t)b*32*H_ + t*H_ + h] = f2bf(val);
    }
  }
}

// ---------------- qh = query @ Wq^T + bq  (per b,mha; MFMA) ----------------
__global__ __launch_bounds__(512) void k_qh(const u16* __restrict__ query_b,
                                            const u16* __restrict__ Wq_b,
                                            const float* __restrict__ taBin,
                                            const float* __restrict__ iaBin,
                                            u16* __restrict__ qh_b){
  int gb = blockIdx.x; int b = gb>>1, mha = gb&1;
  int tid = threadIdx.x, lane = tid&63, w = tid>>6;
  const u16* Q  = query_b + (size_t)b*32*H_;
  const u16* Wq = Wq_b + (size_t)mha*H_*H_;
  const float* bIn = mha? iaBin : taBin;
  u16* out = qh_b + (size_t)gb*32*H_;
  f32x4 acc[2][6];
  #pragma unroll
  for(int i=0;i<2;i++)
    #pragma unroll
    for(int j=0;j<6;j++) acc[i][j] = (f32x4){0.f,0.f,0.f,0.f};
  for(int kt=0;kt<24;kt++){
    int ko = kt*32 + (lane>>4)*8;
    bhalf8 a[2];
    #pragma unroll
    for(int mt=0;mt<2;mt++)
      a[mt] = *(const bhalf8*)(Q + (size_t)(mt*16 + (lane&15))*H_ + ko);
    bhalf8 bb[6];
    #pragma unroll
    for(int j=0;j<6;j++){
      int row = (w*6+j)*16 + (lane&15);
      bb[j] = *(const bhalf8*)(Wq + (size_t)row*H_ + ko);
    }
    #pragma unroll
    for(int mt=0;mt<2;mt++)
      #pragma unroll
      for(int j=0;j<6;j++) acc[mt][j] = mfma16(a[mt], bb[j], acc[mt][j]);
  }
  #pragma unroll
  for(int mt=0;mt<2;mt++)
    #pragma unroll
    for(int j=0;j<6;j++){
      int col = (w*6+j)*16 + (lane&15);
      float bq = bIn[col];
      #pragma unroll
      for(int rr=0;rr<4;rr++){
        int row = mt*16 + (lane>>4)*4 + rr;
        out[(size_t)row*H_ + col] = f2bf(acc[mt][j][rr] + bq);
      }
    }
}

// ---------------- U = qh_h @ Wk_h (rscale folded) + bias ----------------
__global__ __launch_bounds__(512) void k_u(const u16* __restrict__ qh_b,
                                           const u16* __restrict__ WkT,
                                           const float* __restrict__ taBin,
                                           const float* __restrict__ iaBin,
                                           u16* __restrict__ U_b,
                                           float* __restrict__ bias_ws){
  int gb = blockIdx.x; int mha = gb&1;
  int tid = threadIdx.x, lane = tid&63, w = tid>>6;
  const u16* qh = qh_b + (size_t)gb*32*H_;
  const u16* Wk = WkT + (size_t)mha*H_*H_;
  u16* Up = U_b + (size_t)gb*160*H_;
  const float rscale = 0.10206207261596577f;   // 1/sqrt(96)
  for(int h=0; h<8; h++){
    int hd0 = h*HD_;
    for(int jn=0; jn<6; jn++){
      int nb = (w*6+jn)*16 + (lane&15);
      bhalf8 bb[3];
      #pragma unroll
      for(int kt=0;kt<3;kt++)
        bb[kt] = *(const bhalf8*)(Wk + (size_t)nb*H_ + hd0 + kt*32 + (lane>>4)*8);
      #pragma unroll
      for(int mt=0; mt<2; mt++){
        bhalf8 a[3];
        #pragma unroll
        for(int kt=0;kt<3;kt++){
          int trow = mt*16 + (lane&15);
          a[kt] = *(const bhalf8*)(qh + (size_t)trow*H_ + hd0 + kt*32 + (lane>>4)*8);
        }
        f32x4 acc = (f32x4){0.f,0.f,0.f,0.f};
        #pragma unroll
        for(int kt=0;kt<3;kt++) acc = mfma16(a[kt], bb[kt], acc);
        #pragma unroll
        for(int rr=0;rr<4;rr++){
          int trow = mt*16 + (lane>>4)*4 + rr;
          if(trow < T_)
            Up[(size_t)(h*T_+trow)*H_ + nb] = f2bf(acc[rr]*rscale);
        }
      }
    }
  }
  if(tid < 160){
    int h = tid/T_, t = tid%T_; int hd0 = h*HD_;
    const float* bIn = mha? iaBin : taBin;
    float p = 0.f;
    for(int d=0; d<HD_; d++)
      p += bf2f(qh[(size_t)t*H_ + hd0 + d]) * bIn[H_ + hd0 + d];
    bias_ws[gb*160 + tid] = p*rscale;
  }
}

// ---------------- scores + online softmax -> P (bf16) ----------------
__global__ __launch_bounds__(512) void k_scores(const float* __restrict__ ehs,
                                                const u16* __restrict__ U_b,
                                                const float* __restrict__ bias_ws,
                                                const int* __restrict__ smask,
                                                const int* __restrict__ imask,
                                                u16* __restrict__ P_b){
  int gb = blockIdx.x; int b = gb>>1, mha = gb&1;
  const int* msk = mha? imask : smask;
  int tid = threadIdx.x, lane = tid&63, w = tid>>6;
  __shared__ float sc[80][132];
  __shared__ float sbias[160], m_run[160], s_run[160], m_w[4][160];
  for(int r=tid; r<160; r+=512){
    sbias[r] = bias_ws[gb*160 + r];
    m_run[r] = -3e38f; s_run[r] = 0.f;
  }
  __syncthreads();
  const u16* Ub = U_b + (size_t)gb*160*H_;
  u16* Pbase = P_b + (size_t)gb*160*S_;
  int mw = w>>2, ntl = w&3;
  int arow0 = mw*80;
  for(int p=0;p<4;p++){
    f32x4 acc[5][2];
    #pragma unroll
    for(int i=0;i<5;i++)
      #pragma unroll
      for(int j=0;j<2;j++) acc[i][j] = (f32x4){0.f,0.f,0.f,0.f};
    for(int kt=0;kt<24;kt++){
      int ko = kt*32 + (lane>>4)*8;
      bhalf8 a[5];
      #pragma unroll
      for(int i=0;i<5;i++){
        int row = arow0 + i*16 + (lane&15);
        a[i] = *(const bhalf8*)(Ub + (size_t)row*H_ + ko);
      }
      bhalf8 bb[2];
      #pragma unroll
      for(int t2=0;t2<2;t2++){
        int s = p*128 + ntl*32 + t2*16 + (lane&15);
        const float* ep = ehs + ((size_t)b*S_ + s)*H_ + ko;
        float4 v0 = *(const float4*)ep;
        float4 v1 = *(const float4*)(ep+4);
        U8 u;
        u.u[0]=cvtpk(v0.x,v0.y); u.u[1]=cvtpk(v0.z,v0.w);
        u.u[2]=cvtpk(v1.x,v1.y); u.u[3]=cvtpk(v1.z,v1.w);
        bb[t2]=u.s;
      }
      #pragma unroll
      for(int i=0;i<5;i++)
        #pragma unroll
        for(int t2=0;t2<2;t2++) acc[i][t2] = mfma16(a[i], bb[t2], acc[i][t2]);
    }
    // dump + online-softmax stats, one 80-row half at a time
    for(int half=0; half<2; half++){
      __syncthreads();
      if(mw == half){
        #pragma unroll
        for(int i=0;i<5;i++)
          #pragma unroll
          for(int t2=0;t2<2;t2++)
            #pragma unroll
            for(int rr=0;rr<4;rr++){
              int rloc = i*16 + (lane>>4)*4 + rr;
              int cl = ntl*32 + t2*16 + (lane&15);
              sc[rloc][cl] = acc[i][t2][rr];
            }
      }
      __syncthreads();
      for(int ri=0; ri<10; ri++){
        int rloc = w*10 + ri;
        int row = half*80 + rloc;
        float bias = sbias[row];
        float v0 = sc[rloc][lane] + bias;
        float v1 = sc[rloc][lane+64] + bias;
        int sA = p*128 + lane, sB = sA + 64;
        bool mA = msk[b*S_ + sA] != 0;
        bool mB = msk[b*S_ + sB] != 0;
        float mx = fmaxf(mA? v0 : -3e38f, mB? v1 : -3e38f);
        mx = wmaxr(mx);
        float mo = m_run[row];
        float mn = fmaxf(mo, mx);
        float e0 = mA? __expf(v0 - mn) : 0.f;
        float e1 = mB? __expf(v1 - mn) : 0.f;
        float sum = wsum(e0 + e1);
        if(lane==0){
          s_run[row] = s_run[row]*__expf(mo - mn) + sum;
          m_run[row] = mn;
          m_w[p][row] = mn;
        }
        u16* Pp = Pbase + (size_t)row*S_;
        Pp[sA] = f2bf(e0);
        Pp[sB] = f2bf(e1);
      }
    }
  }
  __syncthreads();
  // fixup: rescale each pass-chunk to final max/sum
  for(int ri=0; ri<20; ri++){
    int row = w*20 + ri;
    float mf_ = m_run[row];
    float inv = 1.f/s_run[row];
    u16* Pp = Pbase + (size_t)row*S_;
    for(int p=0;p<4;p++){
      float f = __expf(m_w[p][row] - mf_)*inv;
      int c0 = p*128 + lane;
      float a0 = bf2f(Pp[c0])*f;
      float a1 = bf2f(Pp[c0+64])*f;
      Pp[c0]    = f2bf(a0);
      Pp[c0+64] = f2bf(a1);
    }
  }
}

// ---------------- ctx = P @ ehs (bf16 out) ----------------
__global__ __launch_bounds__(512) void k_ctx(const float* __restrict__ ehs,
                                             const u16* __restrict__ P_b,
                                             u16* __restrict__ ctx_b){
  int gb = blockIdx.x; int b = gb>>1;
  int tid = threadIdx.x, lane = tid&63, w = tid>>6;
  const u16* Pp = P_b + (size_t)gb*160*S_;
  u16* Cp = ctx_b + (size_t)gb*160*H_;
  for(int ch=0; ch<3; ch++){
    f32x4 acc[10][2];
    #pragma unroll
    for(int i=0;i<10;i++)
      #pragma unroll
      for(int j=0;j<2;j++) acc[i][j] = (f32x4){0.f,0.f,0.f,0.f};
    int n0 = ch*256 + w*32;
    for(int kt=0;kt<16;kt++){
      int ko = kt*32 + (lane>>4)*8;
      bhalf8 a[10];
      #pragma unroll
      for(int i=0;i<10;i++){
        int row = i*16 + (lane&15);
        a[i] = *(const bhalf8*)(Pp + (size_t)row*S_ + ko);
      }
      bhalf8 bb[2];
      #pragma unroll
      for(int t2=0;t2<2;t2++){
        int n = n0 + t2*16 + (lane&15);
        const float* ep = ehs + (size_t)b*S_*H_ + n;
        float v[8];
        #pragma unroll
        for(int j=0;j<8;j++) v[j] = ep[(size_t)(ko + j)*H_];
        U8 u;
        u.u[0]=cvtpk(v[0],v[1]); u.u[1]=cvtpk(v[2],v[3]);
        u.u[2]=cvtpk(v[4],v[5]); u.u[3]=cvtpk(v[6],v[7]);
        bb[t2]=u.s;
      }
      #pragma unroll
      for(int i=0;i<10;i++)
        #pragma unroll
        for(int t2=0;t2<2;t2++) acc[i][t2] = mfma16(a[i], bb[t2], acc[i][t2]);
    }
    #pragma unroll
    for(int i=0;i<10;i++)
      #pragma unroll
      for(int t2=0;t2<2;t2++){
        int col = n0 + t2*16 + (lane&15);
        #pragma unroll
        for(int rr=0;rr<4;rr++){
          int row = i*16 + (lane>>4)*4 + rr;
          Cp[(size_t)row*H_ + col] = f2bf(acc[i][t2][rr]);
        }
      }
  }
}

// ---------------- out = (ctx@Wv^T + bv) @ Wout^T  ----------------
__global__ __launch_bounds__(512) void k_out(const u16* __restrict__ ctx_b,
                                             const u16* __restrict__ Wv_b,
                                             const u16* __restrict__ Wo_b,
                                             const float* __restrict__ taBin,
                                             const float* __restrict__ iaBin,
                                             float* __restrict__ out_t,
                                             float* __restrict__ out_i){
  int gb = blockIdx.x; int b = gb>>1, mha = gb&1;
  int tid = threadIdx.x, lane = tid&63, w = tid>>6;
  const float* bIn = mha? iaBin : taBin;
  const u16* Wv = Wv_b + (size_t)mha*H_*H_;
  const u16* Wo = Wo_b + (size_t)mha*H_*H_;
  const u16* Cp = ctx_b + (size_t)gb*160*H_;
  __shared__ u16 vt[32][784];
  // GEMM5: wave w = head w
  int hd0 = w*HD_;
  {
    f32x4 acc[2][6];
    #pragma unroll
    for(int i=0;i<2;i++)
      #pragma unroll
      for(int j=0;j<6;j++) acc[i][j] = (f32x4){0.f,0.f,0.f,0.f};
    for(int kt=0;kt<24;kt++){
      int ko = kt*32 + (lane>>4)*8;
      bhalf8 a[2];
      #pragma unroll
      for(int mt=0;mt<2;mt++){
        int trow = mt*16 + (lane&15);
        a[mt] = *(const bhalf8*)(Cp + (size_t)(w*T_ + trow)*H_ + ko);
      }
      bhalf8 bb[6];
      #pragma unroll
      for(int j=0;j<6;j++){
        int row = hd0 + j*16 + (lane&15);
        bb[j] = *(const bhalf8*)(Wv + (size_t)row*H_ + ko);
      }
      #pragma unroll
      for(int mt=0;mt<2;mt++)
        #pragma unroll
        for(int j=0;j<6;j++) acc[mt][j] = mfma16(a[mt], bb[j], acc[mt][j]);
    }
    #pragma unroll
    for(int mt=0;mt<2;mt++)
      #pragma unroll
      for(int j=0;j<6;j++){
        int col = j*16 + (lane&15);
        float bv = bIn[2*H_ + hd0 + col];
        #pragma unroll
        for(int rr=0;rr<4;rr++){
          int trow = mt*16 + (lane>>4)*4 + rr;
          vt[trow][hd0 + col] = f2bf(acc[mt][j][rr] + bv);
        }
      }
  }
  __syncthreads();
  // GEMM6: out = vt @ Wo^T
  {
    f32x4 o[2][6];
    #pragma unroll
    for(int i=0;i<2;i++)
      #pragma unroll
      for(int j=0;j<6;j++) o[i][j] = (f32x4){0.f,0.f,0.f,0.f};
    for(int kt=0;kt<24;kt++){
      int ko = kt*32 + (lane>>4)*8;
      bhalf8 a[2];
      #pragma unroll
      for(int mt=0;mt<2;mt++)
        a[mt] = *(const bhalf8*)(&vt[mt*16 + (lane&15)][ko]);
      bhalf8 bb[6];
      #pragma unroll
      for(int j=0;j<6;j++){
        int row = (w*6+j)*16 + (lane&15);
        bb[j] = *(const bhalf8*)(Wo + (size_t)row*H_ + ko);
      }
      #pragma unroll
      for(int mt=0;mt<2;mt++)
        #pragma unroll
        for(int j=0;j<6;j++) o[mt][j] = mfma16(a[mt], bb[j], o[mt][j]);
    }
    float* op = (mha? out_i : out_t) + (size_t)b*T_*H_;
    #pragma unroll
    for(int mt=0;mt<2;mt++)
      #pragma unroll
      for(int j=0;j<6;j++){
        int col = (w*6+j)*16 + (lane&15);
        #pragma unroll
        for(int rr=0;rr<4;rr++){
          int trow = mt*16 + (lane>>4)*4 + rr;
          if(trow < T_) op[(size_t)trow*H_ + col] = o[mt][j][rr];
        }
      }
  }
}

// ---------------- comb = beta*(out_i+bi) + (1-beta)*(out_t+bt) (bf16) ----------------
__global__ void k_comb(const float* __restrict__ out_t, const float* __restrict__ out_i,
                       const float* __restrict__ taBout, const float* __restrict__ iaBout,
                       const float* __restrict__ rel, u16* __restrict__ comb_b){
  int bt = blockIdx.x; int b = bt/T_;
  float beta = rel[b];
  for(int h=threadIdx.x; h<H_; h+=256){
    float vt = out_t[(size_t)bt*H_+h] + taBout[h];
    float vi = out_i[(size_t)bt*H_+h] + iaBout[h];
    comb_b[(size_t)bt*H_+h] = f2bf(beta*vi + (1.f-beta)*vt);
  }
}

// ---------------- cap = relu(LN(comb @ laW^T + laB)) ----------------
__global__ __launch_bounds__(512) void k_cap2(const u16* __restrict__ comb_b,
                                              const u16* __restrict__ laW_b,
                                              const float* __restrict__ laB,
                                              const float* __restrict__ laG,
                                              const float* __restrict__ laBe,
                                              float* __restrict__ cap){
  int blk = blockIdx.x; int row0 = blk*16;
  int tid = threadIdx.x, lane = tid&63, w = tid>>6;
  __shared__ float sy[16][776];
  f32x4 acc[6];
  #pragma unroll
  for(int j=0;j<6;j++) acc[j] = (f32x4){0.f,0.f,0.f,0.f};
  for(int kt=0;kt<24;kt++){
    int ko = kt*32 + (lane>>4)*8;
    bhalf8 a = *(const bhalf8*)(comb_b + (size_t)(row0 + (lane&15))*H_ + ko);
    bhalf8 bb[6];
    #pragma unroll
    for(int j=0;j<6;j++){
      int row = (w*6+j)*16 + (lane&15);
      bb[j] = *(const bhalf8*)(laW_b + (size_t)row*H_ + ko);
    }
    #pragma unroll
    for(int j=0;j<6;j++) acc[j] = mfma16(a, bb[j], acc[j]);
  }
  #pragma unroll
  for(int j=0;j<6;j++){
    int c = (w*6+j)*16 + (lane&15);
    float lb = laB[c];
    #pragma unroll
    for(int rr=0;rr<4;rr++){
      int r = (lane>>4)*4 + rr;
      sy[r][c] = acc[j][rr] + lb;
    }
  }
  __syncthreads();
  for(int ri=0; ri<2; ri++){
    int r = w*2 + ri;
    float v[12];
    float s = 0.f;
    #pragma unroll
    for(int i=0;i<12;i++){ v[i] = sy[r][lane + 64*i]; s += v[i]; }
    s = wsum(s);
    float mean = s/(float)H_;
    float pv = 0.f;
    #pragma unroll
    for(int i=0;i<12;i++){ float d = v[i]-mean; pv += d*d; }
    pv = wsum(pv);
    float rstd = rsqrtf(pv/(float)H_ + 1e-5f);
    float* cp = cap + (size_t)(row0 + r)*H_;
    #pragma unroll
    for(int i=0;i<12;i++){
      int c = lane + 64*i;
      float o = (v[i]-mean)*rstd*laG[c] + laBe[c];
      cp[c] = (o>0.f)? o : 0.f;
    }
  }
}

// ---------------- mean over T, quality head ----------------
__global__ void k_mean(const float* __restrict__ cap, float* __restrict__ m){
  int b=blockIdx.x, tid=threadIdx.x;
  for(int hh=tid;hh<H_;hh+=256){
    float s=0.f;
    for(int t=0;t<T_;t++) s += cap[((size_t)b*T_+t)*H_+hh];
    m[b*H_+hh] = s*(1.f/(float)T_);
  }
}

__global__ void k_quality(const float* __restrict__ m, const float* __restrict__ qW1,
                          const float* __restrict__ qB1, const float* __restrict__ qG,
                          const float* __restrict__ qBe, const float* __restrict__ qW2,
                          const float* __restrict__ qB2, float* __restrict__ outq){
  int b=blockIdx.x, tid=threadIdx.x, lane=tid&63, w=tid>>6;
  const int H2 = H_/2;
  __shared__ float sx[H_], sh[H_/2];
  __shared__ float red[4];
  for(int j=tid;j<H_;j+=256) sx[j]=m[b*H_+j];
  __syncthreads();
  for(int j=w;j<H2;j+=4){
    const float* row = qW1 + (size_t)j*H_;
    float p=0.f;
    for(int k=lane;k<H_;k+=64) p += sx[k]*row[k];
    p=wsum(p);
    if(lane==0) sh[j]=p+qB1[j];
  }
  __syncthreads();
  float ps=0.f; for(int j=tid;j<H2;j+=256) ps+=sh[j];
  ps=wsum(ps); if(lane==0) red[w]=ps;
  __syncthreads();
  float mean=(red[0]+red[1]+red[2]+red[3])/(float)H2;
  __syncthreads();
  float pv=0.f; for(int j=tid;j<H2;j+=256){ float d=sh[j]-mean; pv+=d*d; }
  pv=wsum(pv); if(lane==0) red[w]=pv;
  __syncthreads();
  float rstd=rsqrtf((red[0]+red[1]+red[2]+red[3])/(float)H2 + 1e-5f);
  __syncthreads();
  float dot=0.f;
  for(int j=tid;j<H2;j+=256){
    float v=(sh[j]-mean)*rstd*qG[j]+qBe[j];
    v = (v>0.f)? v:0.f;
    dot += v*qW2[j];
  }
  dot=wsum(dot); if(lane==0) red[w]=dot;
  __syncthreads();
  if(tid==0){
    float z = red[0]+red[1]+red[2]+red[3]+qB2[0];
    outq[b] = 1.f/(1.f+expf(-z));
  }
}

extern "C" void kernel_launch(void* const* d_in, const int* in_sizes, int n_in,
                              void* d_out, int out_size, void* d_ws, size_t ws_size,
                              hipStream_t stream){
  const float* ehs    = (const float*)d_in[0];
  const float* rel    = (const float*)d_in[1];
  const float* tW1    = (const float*)d_in[3];
  const float* tb1    = (const float*)d_in[4];
  const float* tg     = (const float*)d_in[5];
  const float* tbe    = (const float*)d_in[6];
  const float* tW2    = (const float*)d_in[7];
  const float* tb2    = (const float*)d_in[8];
  const float* iW1    = (const float*)d_in[9];
  const float* ib1    = (const float*)d_in[10];
  const float* ig     = (const float*)d_in[11];
  const float* ibe    = (const float*)d_in[12];
  const float* iW2    = (const float*)d_in[13];
  const float* ib2    = (const float*)d_in[14];
  const float* taWin  = (const float*)d_in[15];
  const float* taBin  = (const float*)d_in[16];
  const float* taWout = (const float*)d_in[17];
  const float* taBout = (const float*)d_in[18];
  const float* iaWin  = (const float*)d_in[19];
  const float* iaBin  = (const float*)d_in[20];
  const float* iaWout = (const float*)d_in[21];
  const float* iaBout = (const float*)d_in[22];
  const float* laW    = (const float*)d_in[23];
  const float* laB    = (const float*)d_in[24];
  const float* laG    = (const float*)d_in[25];
  const float* laBe   = (const float*)d_in[26];
  const float* qW1    = (const float*)d_in[27];
  const float* qB1    = (const float*)d_in[28];
  const float* qG     = (const float*)d_in[29];
  const float* qBe    = (const float*)d_in[30];
  const float* qW2    = (const float*)d_in[31];
  const float* qB2    = (const float*)d_in[32];
  const int* smask    = (const int*)d_in[33];
  const int* imask    = (const int*)d_in[34];

  char* p = (char*)d_ws;
  auto take = [&](size_t bytes)->char*{
    char* r = p; p += (bytes + 255) & ~(size_t)255; return r;
  };
  float* pt      = (float*)take((size_t)B_*H_*4);
  float* pi      = (float*)take((size_t)B_*H_*4);
  float* st      = (float*)take((size_t)B_*H_*4);
  float* si      = (float*)take((size_t)B_*H_*4);
  u16*  query_b  = (u16*)take((size_t)B_*32*H_*2);
  u16*  qh_b     = (u16*)take((size_t)B_*2*32*H_*2);
  u16*  WkT      = (u16*)take((size_t)2*H_*H_*2);
  u16*  Wq_b     = (u16*)take((size_t)2*H_*H_*2);
  u16*  Wv_b     = (u16*)take((size_t)2*H_*H_*2);
  u16*  Wo_b     = (u16*)take((size_t)2*H_*H_*2);
  u16*  laW_b    = (u16*)take((size_t)H_*H_*2);
  float* bias_ws = (float*)take((size_t)B_*2*160*4);
  u16*  U_b      = (u16*)take((size_t)B_*2*160*H_*2);   // aliased by ctx_b
  u16*  P_b      = (u16*)take((size_t)B_*2*160*S_*2);
  float* out_t   = (float*)take((size_t)B_*T_*H_*4);
  float* out_i   = (float*)take((size_t)B_*T_*H_*4);
  u16*  comb_b   = (u16*)take((size_t)B_*T_*H_*2);
  float* mbuf    = (float*)take((size_t)B_*H_*4);
  u16*  ctx_b    = U_b;

  const int nW2 = (H_*H_)/2;   // pairs per 768x768 matrix
  const int cvtg = (nW2 + 255)/256;

  // weight conversions
  hipLaunchKernelGGL(k_cvt, dim3(cvtg), dim3(256), 0, stream, taWin,              Wq_b,           nW2);
  hipLaunchKernelGGL(k_cvt, dim3(cvtg), dim3(256), 0, stream, iaWin,              Wq_b + (size_t)H_*H_, nW2);
  hipLaunchKernelGGL(k_cvt, dim3(cvtg), dim3(256), 0, stream, taWin + 2*H_*H_,    Wv_b,           nW2);
  hipLaunchKernelGGL(k_cvt, dim3(cvtg), dim3(256), 0, stream, iaWin + 2*H_*H_,    Wv_b + (size_t)H_*H_, nW2);
  hipLaunchKernelGGL(k_cvt, dim3(cvtg), dim3(256), 0, stream, taWout,             Wo_b,           nW2);
  hipLaunchKernelGGL(k_cvt, dim3(cvtg), dim3(256), 0, stream, iaWout,             Wo_b + (size_t)H_*H_, nW2);
  hipLaunchKernelGGL(k_cvt, dim3(cvtg), dim3(256), 0, stream, laW,                laW_b,          nW2);
  hipLaunchKernelGGL(k_wkt, dim3(1152), dim3(256), 0, stream, taWin, iaWin, WkT);

  // pooling + seeds + query
  hipLaunchKernelGGL(k_pool,  dim3(B_*3), dim3(256), 0, stream, ehs, smask, imask, pt, pi);
  hipLaunchKernelGGL(k_proj,  dim3(B_),   dim3(256), 0, stream, pt, tW1, tb1, tg, tbe, tW2, tb2, st);
  hipLaunchKernelGGL(k_proj,  dim3(B_),   dim3(256), 0, stream, pi, iW1, ib1, ig, ibe, iW2, ib2, si);
  hipLaunchKernelGGL(k_query, dim3(B_),   dim3(256), 0, stream, st, si, rel, query_b);

  // attention pipeline
  hipLaunchKernelGGL(k_qh,     dim3(B_*2), dim3(512), 0, stream, query_b, Wq_b, taBin, iaBin, qh_b);
  hipLaunchKernelGGL(k_u,      dim3(B_*2), dim3(512), 0, stream, qh_b, WkT, taBin, iaBin, U_b, bias_ws);
  hipLaunchKernelGGL(k_scores, dim3(B_*2), dim3(512), 0, stream, ehs, U_b, bias_ws, smask, imask, P_b);
  hipLaunchKernelGGL(k_ctx,    dim3(B_*2), dim3(512), 0, stream, ehs, P_b, ctx_b);
  hipLaunchKernelGGL(k_out,    dim3(B_*2), dim3(512), 0, stream, ctx_b, Wv_b, Wo_b, taBin, iaBin, out_t, out_i);

  // epilogue
  float* cap = (float*)d_out;
  hipLaunchKernelGGL(k_comb, dim3(B_*T_), dim3(256), 0, stream, out_t, out_i, taBout, iaBout, rel, comb_b);
  hipLaunchKernelGGL(k_cap2, dim3((B_*T_)/16), dim3(512), 0, stream, comb_b, laW_b, laB, laG, laBe, cap);
  hipLaunchKernelGGL(k_mean, dim3(B_), dim3(256), 0, stream, cap, mbuf);
  hipLaunchKernelGGL(k_quality, dim3(B_), dim3(256), 0, stream,
                     mbuf, qW1, qB1, qG, qBe, qW2, qB2, cap + (size_t)B_*T_*H_);
}

// Round 3
// 1391.465 us; speedup vs baseline: 8.1430x; 3.3422x over previous
//
#include <hip/hip_runtime.h>
#include <hip/hip_bf16.h>
#include <math.h>

#define B_  128
#define S_  512
#define H_  768
#define NH_ 8
#define T_  20
#define HD_ 96

typedef unsigned short u16;
typedef unsigned int   u32;

typedef __attribute__((ext_vector_type(8))) short bhalf8;
typedef __attribute__((ext_vector_type(4))) float f32x4;

union U8 { bhalf8 s; u32 u[4]; };

__device__ __forceinline__ f32x4 mfma16(bhalf8 a, bhalf8 b, f32x4 c){
  return __builtin_amdgcn_mfma_f32_16x16x32_bf16(a, b, c, 0, 0, 0);
}
__device__ __forceinline__ u32 cvtpk(float lo, float hi){
  u32 r; asm volatile("v_cvt_pk_bf16_f32 %0, %1, %2" : "=v"(r) : "v"(lo), "v"(hi));
  return r;
}
__device__ __forceinline__ float wsum(float v){
  #pragma unroll
  for(int o=32;o;o>>=1) v += __shfl_xor(v,o);
  return v;
}
__device__ __forceinline__ float wmaxr(float v){
  #pragma unroll
  for(int o=32;o;o>>=1) v = fmaxf(v, __shfl_xor(v,o));
  return v;
}
__device__ __forceinline__ u16 f2bf(float f){
  u32 u = __float_as_uint(f);
  u32 r = (u + 0x7fffu + ((u>>16)&1u)) >> 16;
  return (u16)r;
}
__device__ __forceinline__ float bf2f(u32 bits){
  return __uint_as_float(bits<<16);
}

// ---------------- generic f32 -> bf16 (pairs) ----------------
__global__ void k_cvt(const float* __restrict__ src, u16* __restrict__ dst, int n2){
  int i = blockIdx.x*256 + threadIdx.x;
  if(i < n2){
    u32 r = cvtpk(src[2*i], src[2*i+1]);
    *(u32*)(dst + 2*i) = r;
  }
}

// ---------------- WkT[mha][n][k] = Wk[k][n] (bf16) ----------------
__global__ void k_wkt(const float* __restrict__ taWin, const float* __restrict__ iaWin,
                      u16* __restrict__ WkT){
  int blk = blockIdx.x; int mha = blk/576; int t = blk%576;
  const float* Wk = (mha? iaWin : taWin) + (size_t)H_*H_;
  int bx = t%24, by = t/24;
  __shared__ float tile[32][33];
  int tx = threadIdx.x & 31, ty = threadIdx.x >> 5;
  for(int rr=ty; rr<32; rr+=8) tile[rr][tx] = Wk[(size_t)(by*32+rr)*H_ + bx*32+tx];
  __syncthreads();
  u16* dst = WkT + (size_t)mha*H_*H_;
  for(int rr=ty; rr<32; rr+=8) dst[(size_t)(bx*32+rr)*H_ + by*32+tx] = f2bf(tile[tx][rr]);
}

// ---------------- pooling (bf16 out) ----------------
__global__ void k_pool(const float* __restrict__ ehs, const int* __restrict__ sm,
                       const int* __restrict__ im, u16* __restrict__ pt_b, u16* __restrict__ pi_b){
  int blk = blockIdx.x; int b = blk/3; int c0 = (blk%3)*256;
  int tid = threadIdx.x;
  __shared__ float smf[S_], imf[S_];
  for(int s=tid;s<S_;s+=256){ smf[s]=(float)sm[b*S_+s]; imf[s]=(float)im[b*S_+s]; }
  __syncthreads();
  float tl=0.f, il=0.f;
  for(int s=0;s<S_;s++){ tl+=smf[s]; il+=imf[s]; }
  tl = fmaxf(tl, 1e-9f); il = fmaxf(il, 1e-9f);
  int col = c0 + tid;
  const float* base = ehs + (size_t)b*S_*H_ + col;
  float ts=0.f, is=0.f;
  for(int s=0;s<S_;s++){
    float a = base[(size_t)s*H_];
    ts += a*smf[s];
    is += a*imf[s];
  }
  pt_b[b*H_+col] = f2bf(ts/tl);
  pi_b[b*H_+col] = f2bf(is/il);
}

// ------ fused seed proj: leaky(x@W1^T+b1) -> LN -> @W2^T+b2  (MFMA, 16 rows/block) ------
__global__ __launch_bounds__(512) void k_seed(const u16* __restrict__ x_b,
                                              const u16* __restrict__ W1_b,
                                              const float* __restrict__ b1,
                                              const float* __restrict__ g,
                                              const float* __restrict__ be,
                                              const u16* __restrict__ W2_b,
                                              const float* __restrict__ b2,
                                              float* __restrict__ out){
  int row0 = blockIdx.x*16;
  int tid = threadIdx.x, lane = tid&63, w = tid>>6;
  __shared__ u16 ln[16][772];   // stride 772 u16 = 386 dw; 386%32==2 -> even bank spread
  // GEMM1: h = x @ W1^T
  f32x4 acc[6];
  #pragma unroll
  for(int j=0;j<6;j++) acc[j] = (f32x4){0.f,0.f,0.f,0.f};
  for(int kt=0;kt<24;kt++){
    int ko = kt*32 + (lane>>4)*8;
    bhalf8 a = *(const bhalf8*)(x_b + (size_t)(row0 + (lane&15))*H_ + ko);
    bhalf8 bb[6];
    #pragma unroll
    for(int j=0;j<6;j++){
      int row = (w*6+j)*16 + (lane&15);
      bb[j] = *(const bhalf8*)(W1_b + (size_t)row*H_ + ko);
    }
    #pragma unroll
    for(int j=0;j<6;j++) acc[j] = mfma16(a, bb[j], acc[j]);
  }
  #pragma unroll
  for(int j=0;j<6;j++){
    int c = (w*6+j)*16 + (lane&15);
    float bv = b1[c];
    #pragma unroll
    for(int rr=0;rr<4;rr++){
      int r = (lane>>4)*4 + rr;
      float v = acc[j][rr] + bv;
      ln[r][c] = f2bf((v>=0.f)? v : 0.01f*v);
    }
  }
  __syncthreads();
  // LN per row (wave w owns rows w*2, w*2+1)
  for(int ri=0; ri<2; ri++){
    int r = w*2 + ri;
    float v[12]; float s = 0.f;
    #pragma unroll
    for(int i=0;i<12;i++){ v[i] = bf2f(ln[r][lane + 64*i]); s += v[i]; }
    s = wsum(s);
    float mean = s/(float)H_;
    float pv = 0.f;
    #pragma unroll
    for(int i=0;i<12;i++){ float d = v[i]-mean; pv += d*d; }
    pv = wsum(pv);
    float rstd = rsqrtf(pv/(float)H_ + 1e-5f);
    #pragma unroll
    for(int i=0;i<12;i++){
      int c = lane + 64*i;
      ln[r][c] = f2bf((v[i]-mean)*rstd*g[c] + be[c]);
    }
  }
  __syncthreads();
  // GEMM2: out = ln @ W2^T + b2
  f32x4 o[6];
  #pragma unroll
  for(int j=0;j<6;j++) o[j] = (f32x4){0.f,0.f,0.f,0.f};
  for(int kt=0;kt<24;kt++){
    int ko = kt*32 + (lane>>4)*8;
    bhalf8 a = *(const bhalf8*)(&ln[lane&15][ko]);
    bhalf8 bb[6];
    #pragma unroll
    for(int j=0;j<6;j++){
      int row = (w*6+j)*16 + (lane&15);
      bb[j] = *(const bhalf8*)(W2_b + (size_t)row*H_ + ko);
    }
    #pragma unroll
    for(int j=0;j<6;j++) o[j] = mfma16(a, bb[j], o[j]);
  }
  #pragma unroll
  for(int j=0;j<6;j++){
    int c = (w*6+j)*16 + (lane&15);
    float bv = b2[c];
    #pragma unroll
    for(int rr=0;rr<4;rr++){
      int r = (lane>>4)*4 + rr;
      out[(size_t)(row0 + r)*H_ + c] = o[j][rr] + bv;
    }
  }
}

// ---------------- query (padded to 32 rows, bf16) ----------------
__global__ void k_query(const float* __restrict__ st, const float* __restrict__ si,
                        const float* __restrict__ rel, u16* __restrict__ query_b){
  int b = blockIdx.x; int tid = threadIdx.x;
  float a = rel[b];
  const float c = 9.210340371976184f/(float)H_;  // ln(10000)/H
  for(int t=0;t<32;t++){
    for(int h=tid;h<H_;h+=256){
      float val = 0.f;
      if(t < T_){
        float ang = (float)t * __expf(-(float)(h & ~1) * c);
        float pe  = (h&1)? __cosf(ang) : __sinf(ang);
        val = a*si[b*H_+h] + (1.f-a)*st[b*H_+h] + pe;
      }
      query_b[(size_t)b*32*H_ + t*H_ + h] = f2bf(val);
    }
  }
}

// ---------------- qh = query @ Wq^T + bq  (per b,mha; MFMA) ----------------
__global__ __launch_bounds__(512) void k_qh(const u16* __restrict__ query_b,
                                            const u16* __restrict__ Wq_b,
                                            const float* __restrict__ taBin,
                                            const float* __restrict__ iaBin,
                                            u16* __restrict__ qh_b){
  int gb = blockIdx.x; int b = gb>>1, mha = gb&1;
  int tid = threadIdx.x, lane = tid&63, w = tid>>6;
  const u16* Q  = query_b + (size_t)b*32*H_;
  const u16* Wq = Wq_b + (size_t)mha*H_*H_;
  const float* bIn = mha? iaBin : taBin;
  u16* out = qh_b + (size_t)gb*32*H_;
  f32x4 acc[2][6];
  #pragma unroll
  for(int i=0;i<2;i++)
    #pragma unroll
    for(int j=0;j<6;j++) acc[i][j] = (f32x4){0.f,0.f,0.f,0.f};
  for(int kt=0;kt<24;kt++){
    int ko = kt*32 + (lane>>4)*8;
    bhalf8 a[2];
    #pragma unroll
    for(int mt=0;mt<2;mt++)
      a[mt] = *(const bhalf8*)(Q + (size_t)(mt*16 + (lane&15))*H_ + ko);
    bhalf8 bb[6];
    #pragma unroll
    for(int j=0;j<6;j++){
      int row = (w*6+j)*16 + (lane&15);
      bb[j] = *(const bhalf8*)(Wq + (size_t)row*H_ + ko);
    }
    #pragma unroll
    for(int mt=0;mt<2;mt++)
      #pragma unroll
      for(int j=0;j<6;j++) acc[mt][j] = mfma16(a[mt], bb[j], acc[mt][j]);
  }
  #pragma unroll
  for(int mt=0;mt<2;mt++)
    #pragma unroll
    for(int j=0;j<6;j++){
      int col = (w*6+j)*16 + (lane&15);
      float bq = bIn[col];
      #pragma unroll
      for(int rr=0;rr<4;rr++){
        int row = mt*16 + (lane>>4)*4 + rr;
        out[(size_t)row*H_ + col] = f2bf(acc[mt][j][rr] + bq);
      }
    }
}

// ---------------- U = qh_h @ Wk_h (rscale folded) + bias ----------------
__global__ __launch_bounds__(512) void k_u(const u16* __restrict__ qh_b,
                                           const u16* __restrict__ WkT,
                                           const float* __restrict__ taBin,
                                           const float* __restrict__ iaBin,
                                           u16* __restrict__ U_b,
                                           float* __restrict__ bias_ws){
  int gb = blockIdx.x; int mha = gb&1;
  int tid = threadIdx.x, lane = tid&63, w = tid>>6;
  const u16* qh = qh_b + (size_t)gb*32*H_;
  const u16* Wk = WkT + (size_t)mha*H_*H_;
  u16* Up = U_b + (size_t)gb*160*H_;
  const float rscale = 0.10206207261596577f;   // 1/sqrt(96)
  for(int h=0; h<8; h++){
    int hd0 = h*HD_;
    for(int jn=0; jn<6; jn++){
      int nb = (w*6+jn)*16 + (lane&15);
      bhalf8 bb[3];
      #pragma unroll
      for(int kt=0;kt<3;kt++)
        bb[kt] = *(const bhalf8*)(Wk + (size_t)nb*H_ + hd0 + kt*32 + (lane>>4)*8);
      #pragma unroll
      for(int mt=0; mt<2; mt++){
        bhalf8 a[3];
        #pragma unroll
        for(int kt=0;kt<3;kt++){
          int trow = mt*16 + (lane&15);
          a[kt] = *(const bhalf8*)(qh + (size_t)trow*H_ + hd0 + kt*32 + (lane>>4)*8);
        }
        f32x4 acc = (f32x4){0.f,0.f,0.f,0.f};
        #pragma unroll
        for(int kt=0;kt<3;kt++) acc = mfma16(a[kt], bb[kt], acc);
        #pragma unroll
        for(int rr=0;rr<4;rr++){
          int trow = mt*16 + (lane>>4)*4 + rr;
          if(trow < T_)
            Up[(size_t)(h*T_+trow)*H_ + nb] = f2bf(acc[rr]*rscale);
        }
      }
    }
  }
  if(tid < 160){
    int h = tid/T_, t = tid%T_; int hd0 = h*HD_;
    const float* bIn = mha? iaBin : taBin;
    float p = 0.f;
    for(int d=0; d<HD_; d++)
      p += bf2f(qh[(size_t)t*H_ + hd0 + d]) * bIn[H_ + hd0 + d];
    bias_ws[gb*160 + tid] = p*rscale;
  }
}

// ---------------- scores + online softmax -> P (bf16) ----------------
__global__ __launch_bounds__(512) void k_scores(const float* __restrict__ ehs,
                                                const u16* __restrict__ U_b,
                                                const float* __restrict__ bias_ws,
                                                const int* __restrict__ smask,
                                                const int* __restrict__ imask,
                                                u16* __restrict__ P_b){
  int gb = blockIdx.x; int b = gb>>1, mha = gb&1;
  const int* msk = mha? imask : smask;
  int tid = threadIdx.x, lane = tid&63, w = tid>>6;
  __shared__ float sc[80][132];
  __shared__ float sbias[160], m_run[160], s_run[160], m_w[4][160];
  for(int r=tid; r<160; r+=512){
    sbias[r] = bias_ws[gb*160 + r];
    m_run[r] = -3e38f; s_run[r] = 0.f;
  }
  __syncthreads();
  const u16* Ub = U_b + (size_t)gb*160*H_;
  u16* Pbase = P_b + (size_t)gb*160*S_;
  int mw = w>>2, ntl = w&3;
  int arow0 = mw*80;
  for(int p=0;p<4;p++){
    f32x4 acc[5][2];
    #pragma unroll
    for(int i=0;i<5;i++)
      #pragma unroll
      for(int j=0;j<2;j++) acc[i][j] = (f32x4){0.f,0.f,0.f,0.f};
    for(int kt=0;kt<24;kt++){
      int ko = kt*32 + (lane>>4)*8;
      bhalf8 a[5];
      #pragma unroll
      for(int i=0;i<5;i++){
        int row = arow0 + i*16 + (lane&15);
        a[i] = *(const bhalf8*)(Ub + (size_t)row*H_ + ko);
      }
      bhalf8 bb[2];
      #pragma unroll
      for(int t2=0;t2<2;t2++){
        int s = p*128 + ntl*32 + t2*16 + (lane&15);
        const float* ep = ehs + ((size_t)b*S_ + s)*H_ + ko;
        float4 v0 = *(const float4*)ep;
        float4 v1 = *(const float4*)(ep+4);
        U8 u;
        u.u[0]=cvtpk(v0.x,v0.y); u.u[1]=cvtpk(v0.z,v0.w);
        u.u[2]=cvtpk(v1.x,v1.y); u.u[3]=cvtpk(v1.z,v1.w);
        bb[t2]=u.s;
      }
      #pragma unroll
      for(int i=0;i<5;i++)
        #pragma unroll
        for(int t2=0;t2<2;t2++) acc[i][t2] = mfma16(a[i], bb[t2], acc[i][t2]);
    }
    // dump + online-softmax stats, one 80-row half at a time
    for(int half=0; half<2; half++){
      __syncthreads();
      if(mw == half){
        #pragma unroll
        for(int i=0;i<5;i++)
          #pragma unroll
          for(int t2=0;t2<2;t2++)
            #pragma unroll
            for(int rr=0;rr<4;rr++){
              int rloc = i*16 + (lane>>4)*4 + rr;
              int cl = ntl*32 + t2*16 + (lane&15);
              sc[rloc][cl] = acc[i][t2][rr];
            }
      }
      __syncthreads();
      for(int ri=0; ri<10; ri++){
        int rloc = w*10 + ri;
        int row = half*80 + rloc;
        float bias = sbias[row];
        float v0 = sc[rloc][lane] + bias;
        float v1 = sc[rloc][lane+64] + bias;
        int sA = p*128 + lane, sB = sA + 64;
        bool mA = msk[b*S_ + sA] != 0;
        bool mB = msk[b*S_ + sB] != 0;
        float mx = fmaxf(mA? v0 : -3e38f, mB? v1 : -3e38f);
        mx = wmaxr(mx);
        float mo = m_run[row];
        float mn = fmaxf(mo, mx);
        float e0 = mA? __expf(v0 - mn) : 0.f;
        float e1 = mB? __expf(v1 - mn) : 0.f;
        float sum = wsum(e0 + e1);
        if(lane==0){
          s_run[row] = s_run[row]*__expf(mo - mn) + sum;
          m_run[row] = mn;
          m_w[p][row] = mn;
        }
        u16* Pp = Pbase + (size_t)row*S_;
        Pp[sA] = f2bf(e0);
        Pp[sB] = f2bf(e1);
      }
    }
  }
  __syncthreads();
  // fixup: rescale each pass-chunk to final max/sum
  for(int ri=0; ri<20; ri++){
    int row = w*20 + ri;
    float mf_ = m_run[row];
    float inv = 1.f/s_run[row];
    u16* Pp = Pbase + (size_t)row*S_;
    for(int p=0;p<4;p++){
      float f = __expf(m_w[p][row] - mf_)*inv;
      int c0 = p*128 + lane;
      float a0 = bf2f(Pp[c0])*f;
      float a1 = bf2f(Pp[c0+64])*f;
      Pp[c0]    = f2bf(a0);
      Pp[c0+64] = f2bf(a1);
    }
  }
}

// ---------------- ctx = P @ ehs (bf16 out) ----------------
__global__ __launch_bounds__(512) void k_ctx(const float* __restrict__ ehs,
                                             const u16* __restrict__ P_b,
                                             u16* __restrict__ ctx_b){
  int gb = blockIdx.x; int b = gb>>1;
  int tid = threadIdx.x, lane = tid&63, w = tid>>6;
  const u16* Pp = P_b + (size_t)gb*160*S_;
  u16* Cp = ctx_b + (size_t)gb*160*H_;
  for(int ch=0; ch<3; ch++){
    f32x4 acc[10][2];
    #pragma unroll
    for(int i=0;i<10;i++)
      #pragma unroll
      for(int j=0;j<2;j++) acc[i][j] = (f32x4){0.f,0.f,0.f,0.f};
    int n0 = ch*256 + w*32;
    for(int kt=0;kt<16;kt++){
      int ko = kt*32 + (lane>>4)*8;
      bhalf8 a[10];
      #pragma unroll
      for(int i=0;i<10;i++){
        int row = i*16 + (lane&15);
        a[i] = *(const bhalf8*)(Pp + (size_t)row*S_ + ko);
      }
      bhalf8 bb[2];
      #pragma unroll
      for(int t2=0;t2<2;t2++){
        int n = n0 + t2*16 + (lane&15);
        const float* ep = ehs + (size_t)b*S_*H_ + n;
        float v[8];
        #pragma unroll
        for(int j=0;j<8;j++) v[j] = ep[(size_t)(ko + j)*H_];
        U8 u;
        u.u[0]=cvtpk(v[0],v[1]); u.u[1]=cvtpk(v[2],v[3]);
        u.u[2]=cvtpk(v[4],v[5]); u.u[3]=cvtpk(v[6],v[7]);
        bb[t2]=u.s;
      }
      #pragma unroll
      for(int i=0;i<10;i++)
        #pragma unroll
        for(int t2=0;t2<2;t2++) acc[i][t2] = mfma16(a[i], bb[t2], acc[i][t2]);
    }
    #pragma unroll
    for(int i=0;i<10;i++)
      #pragma unroll
      for(int t2=0;t2<2;t2++){
        int col = n0 + t2*16 + (lane&15);
        #pragma unroll
        for(int rr=0;rr<4;rr++){
          int row = i*16 + (lane>>4)*4 + rr;
          Cp[(size_t)row*H_ + col] = f2bf(acc[i][t2][rr]);
        }
      }
  }
}

// ---------------- out = (ctx@Wv^T + bv) @ Wout^T  ----------------
__global__ __launch_bounds__(512) void k_out(const u16* __restrict__ ctx_b,
                                             const u16* __restrict__ Wv_b,
                                             const u16* __restrict__ Wo_b,
                                             const float* __restrict__ taBin,
                                             const float* __restrict__ iaBin,
                                             float* __restrict__ out_t,
                                             float* __restrict__ out_i){
  int gb = blockIdx.x; int b = gb>>1, mha = gb&1;
  int tid = threadIdx.x, lane = tid&63, w = tid>>6;
  const float* bIn = mha? iaBin : taBin;
  const u16* Wv = Wv_b + (size_t)mha*H_*H_;
  const u16* Wo = Wo_b + (size_t)mha*H_*H_;
  const u16* Cp = ctx_b + (size_t)gb*160*H_;
  __shared__ u16 vt[32][784];
  // GEMM5: wave w = head w
  int hd0 = w*HD_;
  {
    f32x4 acc[2][6];
    #pragma unroll
    for(int i=0;i<2;i++)
      #pragma unroll
      for(int j=0;j<6;j++) acc[i][j] = (f32x4){0.f,0.f,0.f,0.f};
    for(int kt=0;kt<24;kt++){
      int ko = kt*32 + (lane>>4)*8;
      bhalf8 a[2];
      #pragma unroll
      for(int mt=0;mt<2;mt++){
        int trow = mt*16 + (lane&15);
        a[mt] = *(const bhalf8*)(Cp + (size_t)(w*T_ + trow)*H_ + ko);
      }
      bhalf8 bb[6];
      #pragma unroll
      for(int j=0;j<6;j++){
        int row = hd0 + j*16 + (lane&15);
        bb[j] = *(const bhalf8*)(Wv + (size_t)row*H_ + ko);
      }
      #pragma unroll
      for(int mt=0;mt<2;mt++)
        #pragma unroll
        for(int j=0;j<6;j++) acc[mt][j] = mfma16(a[mt], bb[j], acc[mt][j]);
    }
    #pragma unroll
    for(int mt=0;mt<2;mt++)
      #pragma unroll
      for(int j=0;j<6;j++){
        int col = j*16 + (lane&15);
        float bv = bIn[2*H_ + hd0 + col];
        #pragma unroll
        for(int rr=0;rr<4;rr++){
          int trow = mt*16 + (lane>>4)*4 + rr;
          vt[trow][hd0 + col] = f2bf(acc[mt][j][rr] + bv);
        }
      }
  }
  __syncthreads();
  // GEMM6: out = vt @ Wo^T
  {
    f32x4 o[2][6];
    #pragma unroll
    for(int i=0;i<2;i++)
      #pragma unroll
      for(int j=0;j<6;j++) o[i][j] = (f32x4){0.f,0.f,0.f,0.f};
    for(int kt=0;kt<24;kt++){
      int ko = kt*32 + (lane>>4)*8;
      bhalf8 a[2];
      #pragma unroll
      for(int mt=0;mt<2;mt++)
        a[mt] = *(const bhalf8*)(&vt[mt*16 + (lane&15)][ko]);
      bhalf8 bb[6];
      #pragma unroll
      for(int j=0;j<6;j++){
        int row = (w*6+j)*16 + (lane&15);
        bb[j] = *(const bhalf8*)(Wo + (size_t)row*H_ + ko);
      }
      #pragma unroll
      for(int mt=0;mt<2;mt++)
        #pragma unroll
        for(int j=0;j<6;j++) o[mt][j] = mfma16(a[mt], bb[j], o[mt][j]);
    }
    float* op = (mha? out_i : out_t) + (size_t)b*T_*H_;
    #pragma unroll
    for(int mt=0;mt<2;mt++)
      #pragma unroll
      for(int j=0;j<6;j++){
        int col = (w*6+j)*16 + (lane&15);
        #pragma unroll
        for(int rr=0;rr<4;rr++){
          int trow = mt*16 + (lane>>4)*4 + rr;
          if(trow < T_) op[(size_t)trow*H_ + col] = o[mt][j][rr];
        }
      }
  }
}

// ---------------- comb = beta*(out_i+bi) + (1-beta)*(out_t+bt) (bf16) ----------------
__global__ void k_comb(const float* __restrict__ out_t, const float* __restrict__ out_i,
                       const float* __restrict__ taBout, const float* __restrict__ iaBout,
                       const float* __restrict__ rel, u16* __restrict__ comb_b){
  int bt = blockIdx.x; int b = bt/T_;
  float beta = rel[b];
  for(int h=threadIdx.x; h<H_; h+=256){
    float vt = out_t[(size_t)bt*H_+h] + taBout[h];
    float vi = out_i[(size_t)bt*H_+h] + iaBout[h];
    comb_b[(size_t)bt*H_+h] = f2bf(beta*vi + (1.f-beta)*vt);
  }
}

// ---------------- cap = relu(LN(comb @ laW^T + laB)) ----------------
__global__ __launch_bounds__(512) void k_cap2(const u16* __restrict__ comb_b,
                                              const u16* __restrict__ laW_b,
                                              const float* __restrict__ laB,
                                              const float* __restrict__ laG,
                                              const float* __restrict__ laBe,
                                              float* __restrict__ cap){
  int blk = blockIdx.x; int row0 = blk*16;
  int tid = threadIdx.x, lane = tid&63, w = tid>>6;
  __shared__ float sy[16][776];
  f32x4 acc[6];
  #pragma unroll
  for(int j=0;j<6;j++) acc[j] = (f32x4){0.f,0.f,0.f,0.f};
  for(int kt=0;kt<24;kt++){
    int ko = kt*32 + (lane>>4)*8;
    bhalf8 a = *(const bhalf8*)(comb_b + (size_t)(row0 + (lane&15))*H_ + ko);
    bhalf8 bb[6];
    #pragma unroll
    for(int j=0;j<6;j++){
      int row = (w*6+j)*16 + (lane&15);
      bb[j] = *(const bhalf8*)(laW_b + (size_t)row*H_ + ko);
    }
    #pragma unroll
    for(int j=0;j<6;j++) acc[j] = mfma16(a, bb[j], acc[j]);
  }
  #pragma unroll
  for(int j=0;j<6;j++){
    int c = (w*6+j)*16 + (lane&15);
    float lb = laB[c];
    #pragma unroll
    for(int rr=0;rr<4;rr++){
      int r = (lane>>4)*4 + rr;
      sy[r][c] = acc[j][rr] + lb;
    }
  }
  __syncthreads();
  for(int ri=0; ri<2; ri++){
    int r = w*2 + ri;
    float v[12];
    float s = 0.f;
    #pragma unroll
    for(int i=0;i<12;i++){ v[i] = sy[r][lane + 64*i]; s += v[i]; }
    s = wsum(s);
    float mean = s/(float)H_;
    float pv = 0.f;
    #pragma unroll
    for(int i=0;i<12;i++){ float d = v[i]-mean; pv += d*d; }
    pv = wsum(pv);
    float rstd = rsqrtf(pv/(float)H_ + 1e-5f);
    float* cp = cap + (size_t)(row0 + r)*H_;
    #pragma unroll
    for(int i=0;i<12;i++){
      int c = lane + 64*i;
      float o = (v[i]-mean)*rstd*laG[c] + laBe[c];
      cp[c] = (o>0.f)? o : 0.f;
    }
  }
}

// ---------------- mean over T, quality head ----------------
__global__ void k_mean(const float* __restrict__ cap, float* __restrict__ m){
  int b=blockIdx.x, tid=threadIdx.x;
  for(int hh=tid;hh<H_;hh+=256){
    float s=0.f;
    for(int t=0;t<T_;t++) s += cap[((size_t)b*T_+t)*H_+hh];
    m[b*H_+hh] = s*(1.f/(float)T_);
  }
}

__global__ void k_quality(const float* __restrict__ m, const float* __restrict__ qW1,
                          const float* __restrict__ qB1, const float* __restrict__ qG,
                          const float* __restrict__ qBe, const float* __restrict__ qW2,
                          const float* __restrict__ qB2, float* __restrict__ outq){
  int b=blockIdx.x, tid=threadIdx.x, lane=tid&63, w=tid>>6;
  const int H2 = H_/2;
  __shared__ float sx[H_], sh[H_/2];
  __shared__ float red[4];
  for(int j=tid;j<H_;j+=256) sx[j]=m[b*H_+j];
  __syncthreads();
  for(int j=w;j<H2;j+=4){
    const float* row = qW1 + (size_t)j*H_;
    float p=0.f;
    for(int k=lane;k<H_;k+=64) p += sx[k]*row[k];
    p=wsum(p);
    if(lane==0) sh[j]=p+qB1[j];
  }
  __syncthreads();
  float ps=0.f; for(int j=tid;j<H2;j+=256) ps+=sh[j];
  ps=wsum(ps); if(lane==0) red[w]=ps;
  __syncthreads();
  float mean=(red[0]+red[1]+red[2]+red[3])/(float)H2;
  __syncthreads();
  float pv=0.f; for(int j=tid;j<H2;j+=256){ float d=sh[j]-mean; pv+=d*d; }
  pv=wsum(pv); if(lane==0) red[w]=pv;
  __syncthreads();
  float rstd=rsqrtf((red[0]+red[1]+red[2]+red[3])/(float)H2 + 1e-5f);
  __syncthreads();
  float dot=0.f;
  for(int j=tid;j<H2;j+=256){
    float v=(sh[j]-mean)*rstd*qG[j]+qBe[j];
    v = (v>0.f)? v:0.f;
    dot += v*qW2[j];
  }
  dot=wsum(dot); if(lane==0) red[w]=dot;
  __syncthreads();
  if(tid==0){
    float z = red[0]+red[1]+red[2]+red[3]+qB2[0];
    outq[b] = 1.f/(1.f+expf(-z));
  }
}

extern "C" void kernel_launch(void* const* d_in, const int* in_sizes, int n_in,
                              void* d_out, int out_size, void* d_ws, size_t ws_size,
                              hipStream_t stream){
  const float* ehs    = (const float*)d_in[0];
  const float* rel    = (const float*)d_in[1];
  const float* tW1    = (const float*)d_in[3];
  const float* tb1    = (const float*)d_in[4];
  const float* tg     = (const float*)d_in[5];
  const float* tbe    = (const float*)d_in[6];
  const float* tW2    = (const float*)d_in[7];
  const float* tb2    = (const float*)d_in[8];
  const float* iW1    = (const float*)d_in[9];
  const float* ib1    = (const float*)d_in[10];
  const float* ig     = (const float*)d_in[11];
  const float* ibe    = (const float*)d_in[12];
  const float* iW2    = (const float*)d_in[13];
  const float* ib2    = (const float*)d_in[14];
  const float* taWin  = (const float*)d_in[15];
  const float* taBin  = (const float*)d_in[16];
  const float* taWout = (const float*)d_in[17];
  const float* taBout = (const float*)d_in[18];
  const float* iaWin  = (const float*)d_in[19];
  const float* iaBin  = (const float*)d_in[20];
  const float* iaWout = (const float*)d_in[21];
  const float* iaBout = (const float*)d_in[22];
  const float* laW    = (const float*)d_in[23];
  const float* laB    = (const float*)d_in[24];
  const float* laG    = (const float*)d_in[25];
  const float* laBe   = (const float*)d_in[26];
  const float* qW1    = (const float*)d_in[27];
  const float* qB1    = (const float*)d_in[28];
  const float* qG     = (const float*)d_in[29];
  const float* qBe    = (const float*)d_in[30];
  const float* qW2    = (const float*)d_in[31];
  const float* qB2    = (const float*)d_in[32];
  const int* smask    = (const int*)d_in[33];
  const int* imask    = (const int*)d_in[34];

  char* p = (char*)d_ws;
  auto take = [&](size_t bytes)->char*{
    char* r = p; p += (bytes + 255) & ~(size_t)255; return r;
  };
  float* st      = (float*)take((size_t)B_*H_*4);
  float* si      = (float*)take((size_t)B_*H_*4);
  u16*  pt_b     = (u16*)take((size_t)B_*H_*2);
  u16*  pi_b     = (u16*)take((size_t)B_*H_*2);
  u16*  query_b  = (u16*)take((size_t)B_*32*H_*2);
  u16*  qh_b     = (u16*)take((size_t)B_*2*32*H_*2);
  u16*  WkT      = (u16*)take((size_t)2*H_*H_*2);
  u16*  Wq_b     = (u16*)take((size_t)2*H_*H_*2);
  u16*  Wv_b     = (u16*)take((size_t)2*H_*H_*2);
  u16*  Wo_b     = (u16*)take((size_t)2*H_*H_*2);
  u16*  laW_b    = (u16*)take((size_t)H_*H_*2);
  u16*  tW1_b    = (u16*)take((size_t)H_*H_*2);
  u16*  tW2_b    = (u16*)take((size_t)H_*H_*2);
  u16*  iW1_b    = (u16*)take((size_t)H_*H_*2);
  u16*  iW2_b    = (u16*)take((size_t)H_*H_*2);
  float* bias_ws = (float*)take((size_t)B_*2*160*4);
  u16*  U_b      = (u16*)take((size_t)B_*2*160*H_*2);   // aliased by ctx_b
  u16*  P_b      = (u16*)take((size_t)B_*2*160*S_*2);
  float* out_t   = (float*)take((size_t)B_*T_*H_*4);
  float* out_i   = (float*)take((size_t)B_*T_*H_*4);
  u16*  comb_b   = (u16*)take((size_t)B_*T_*H_*2);
  float* mbuf    = (float*)take((size_t)B_*H_*4);
  u16*  ctx_b    = U_b;

  const int nW2 = (H_*H_)/2;   // pairs per 768x768 matrix
  const int cvtg = (nW2 + 255)/256;

  // weight conversions
  hipLaunchKernelGGL(k_cvt, dim3(cvtg), dim3(256), 0, stream, taWin,              Wq_b,           nW2);
  hipLaunchKernelGGL(k_cvt, dim3(cvtg), dim3(256), 0, stream, iaWin,              Wq_b + (size_t)H_*H_, nW2);
  hipLaunchKernelGGL(k_cvt, dim3(cvtg), dim3(256), 0, stream, taWin + 2*H_*H_,    Wv_b,           nW2);
  hipLaunchKernelGGL(k_cvt, dim3(cvtg), dim3(256), 0, stream, iaWin + 2*H_*H_,    Wv_b + (size_t)H_*H_, nW2);
  hipLaunchKernelGGL(k_cvt, dim3(cvtg), dim3(256), 0, stream, taWout,             Wo_b,           nW2);
  hipLaunchKernelGGL(k_cvt, dim3(cvtg), dim3(256), 0, stream, iaWout,             Wo_b + (size_t)H_*H_, nW2);
  hipLaunchKernelGGL(k_cvt, dim3(cvtg), dim3(256), 0, stream, laW,                laW_b,          nW2);
  hipLaunchKernelGGL(k_cvt, dim3(cvtg), dim3(256), 0, stream, tW1,                tW1_b,          nW2);
  hipLaunchKernelGGL(k_cvt, dim3(cvtg), dim3(256), 0, stream, tW2,                tW2_b,          nW2);
  hipLaunchKernelGGL(k_cvt, dim3(cvtg), dim3(256), 0, stream, iW1,                iW1_b,          nW2);
  hipLaunchKernelGGL(k_cvt, dim3(cvtg), dim3(256), 0, stream, iW2,                iW2_b,          nW2);
  hipLaunchKernelGGL(k_wkt, dim3(1152), dim3(256), 0, stream, taWin, iaWin, WkT);

  // pooling + seeds + query
  hipLaunchKernelGGL(k_pool,  dim3(B_*3), dim3(256), 0, stream, ehs, smask, imask, pt_b, pi_b);
  hipLaunchKernelGGL(k_seed,  dim3(B_/16), dim3(512), 0, stream, pt_b, tW1_b, tb1, tg, tbe, tW2_b, tb2, st);
  hipLaunchKernelGGL(k_seed,  dim3(B_/16), dim3(512), 0, stream, pi_b, iW1_b, ib1, ig, ibe, iW2_b, ib2, si);
  hipLaunchKernelGGL(k_query, dim3(B_),   dim3(256), 0, stream, st, si, rel, query_b);

  // attention pipeline
  hipLaunchKernelGGL(k_qh,     dim3(B_*2), dim3(512), 0, stream, query_b, Wq_b, taBin, iaBin, qh_b);
  hipLaunchKernelGGL(k_u,      dim3(B_*2), dim3(512), 0, stream, qh_b, WkT, taBin, iaBin, U_b, bias_ws);
  hipLaunchKernelGGL(k_scores, dim3(B_*2), dim3(512), 0, stream, ehs, U_b, bias_ws, smask, imask, P_b);
  hipLaunchKernelGGL(k_ctx,    dim3(B_*2), dim3(512), 0, stream, ehs, P_b, ctx_b);
  hipLaunchKernelGGL(k_out,    dim3(B_*2), dim3(512), 0, stream, ctx_b, Wv_b, Wo_b, taBin, iaBin, out_t, out_i);

  // epilogue
  float* cap = (float*)d_out;
  hipLaunchKernelGGL(k_comb, dim3(B_*T_), dim3(256), 0, stream, out_t, out_i, taBout, iaBout, rel, comb_b);
  hipLaunchKernelGGL(k_cap2, dim3((B_*T_)/16), dim3(512), 0, stream, comb_b, laW_b, laB, laG, laBe, cap);
  hipLaunchKernelGGL(k_mean, dim3(B_), dim3(256), 0, stream, cap, mbuf);
  hipLaunchKernelGGL(k_quality, dim3(B_), dim3(256), 0, stream,
                     mbuf, qW1, qB1, qG, qBe, qW2, qB2, cap + (size_t)B_*T_*H_);
}

// Round 4
// 991.375 us; speedup vs baseline: 11.4293x; 1.4036x over previous
//
#include <hip/hip_runtime.h>
#include <hip/hip_bf16.h>
#include <math.h>

#define B_  128
#define S_  512
#define H_  768
#define NH_ 8
#define T_  20
#define HD_ 96

typedef unsigned short u16;
typedef unsigned int   u32;

typedef __attribute__((ext_vector_type(8))) short bhalf8;
typedef __attribute__((ext_vector_type(4))) float f32x4;

union U8 { bhalf8 s; u32 u[4]; };

__device__ __forceinline__ f32x4 mfma16(bhalf8 a, bhalf8 b, f32x4 c){
  return __builtin_amdgcn_mfma_f32_16x16x32_bf16(a, b, c, 0, 0, 0);
}
__device__ __forceinline__ u32 cvtpk(float lo, float hi){
  u32 r; asm volatile("v_cvt_pk_bf16_f32 %0, %1, %2" : "=v"(r) : "v"(lo), "v"(hi));
  return r;
}
__device__ __forceinline__ float wsum(float v){
  #pragma unroll
  for(int o=32;o;o>>=1) v += __shfl_xor(v,o);
  return v;
}
__device__ __forceinline__ float wmaxr(float v){
  #pragma unroll
  for(int o=32;o;o>>=1) v = fmaxf(v, __shfl_xor(v,o));
  return v;
}
__device__ __forceinline__ u16 f2bf(float f){
  u32 u = __float_as_uint(f);
  u32 r = (u + 0x7fffu + ((u>>16)&1u)) >> 16;
  return (u16)r;
}
__device__ __forceinline__ float bf2f(u32 bits){
  return __uint_as_float(bits<<16);
}

// ---------------- generic f32 -> bf16 (pairs) ----------------
__global__ void k_cvt(const float* __restrict__ src, u16* __restrict__ dst, int n2){
  int i = blockIdx.x*256 + threadIdx.x;
  if(i < n2){
    u32 r = cvtpk(src[2*i], src[2*i+1]);
    *(u32*)(dst + 2*i) = r;
  }
}

// ---------------- WkT[mha][n][k] = Wk[k][n] (bf16) ----------------
__global__ void k_wkt(const float* __restrict__ taWin, const float* __restrict__ iaWin,
                      u16* __restrict__ WkT){
  int blk = blockIdx.x; int mha = blk/576; int t = blk%576;
  const float* Wk = (mha? iaWin : taWin) + (size_t)H_*H_;
  int bx = t%24, by = t/24;
  __shared__ float tile[32][33];
  int tx = threadIdx.x & 31, ty = threadIdx.x >> 5;
  for(int rr=ty; rr<32; rr+=8) tile[rr][tx] = Wk[(size_t)(by*32+rr)*H_ + bx*32+tx];
  __syncthreads();
  u16* dst = WkT + (size_t)mha*H_*H_;
  for(int rr=ty; rr<32; rr+=8) dst[(size_t)(bx*32+rr)*H_ + by*32+tx] = f2bf(tile[tx][rr]);
}

// ---------------- pooling (bf16 out) ----------------
__global__ void k_pool(const float* __restrict__ ehs, const int* __restrict__ sm,
                       const int* __restrict__ im, u16* __restrict__ pt_b, u16* __restrict__ pi_b){
  int blk = blockIdx.x; int b = blk/3; int c0 = (blk%3)*256;
  int tid = threadIdx.x;
  __shared__ float smf[S_], imf[S_];
  for(int s=tid;s<S_;s+=256){ smf[s]=(float)sm[b*S_+s]; imf[s]=(float)im[b*S_+s]; }
  __syncthreads();
  float tl=0.f, il=0.f;
  for(int s=0;s<S_;s++){ tl+=smf[s]; il+=imf[s]; }
  tl = fmaxf(tl, 1e-9f); il = fmaxf(il, 1e-9f);
  int col = c0 + tid;
  const float* base = ehs + (size_t)b*S_*H_ + col;
  float ts=0.f, is=0.f;
  for(int s=0;s<S_;s++){
    float a = base[(size_t)s*H_];
    ts += a*smf[s];
    is += a*imf[s];
  }
  pt_b[b*H_+col] = f2bf(ts/tl);
  pi_b[b*H_+col] = f2bf(is/il);
}

// ------ fused seed proj: leaky(x@W1^T+b1) -> LN -> @W2^T+b2  (MFMA, 16 rows/block) ------
__global__ __launch_bounds__(512) void k_seed(const u16* __restrict__ x_b,
                                              const u16* __restrict__ W1_b,
                                              const float* __restrict__ b1,
                                              const float* __restrict__ g,
                                              const float* __restrict__ be,
                                              const u16* __restrict__ W2_b,
                                              const float* __restrict__ b2,
                                              float* __restrict__ out){
  int row0 = blockIdx.x*16;
  int tid = threadIdx.x, lane = tid&63, w = tid>>6;
  __shared__ u16 ln[16][772];   // stride 772 u16 = 386 dw; 386%32==2 -> even bank spread
  // GEMM1: h = x @ W1^T
  f32x4 acc[6];
  #pragma unroll
  for(int j=0;j<6;j++) acc[j] = (f32x4){0.f,0.f,0.f,0.f};
  for(int kt=0;kt<24;kt++){
    int ko = kt*32 + (lane>>4)*8;
    bhalf8 a = *(const bhalf8*)(x_b + (size_t)(row0 + (lane&15))*H_ + ko);
    bhalf8 bb[6];
    #pragma unroll
    for(int j=0;j<6;j++){
      int row = (w*6+j)*16 + (lane&15);
      bb[j] = *(const bhalf8*)(W1_b + (size_t)row*H_ + ko);
    }
    #pragma unroll
    for(int j=0;j<6;j++) acc[j] = mfma16(a, bb[j], acc[j]);
  }
  #pragma unroll
  for(int j=0;j<6;j++){
    int c = (w*6+j)*16 + (lane&15);
    float bv = b1[c];
    #pragma unroll
    for(int rr=0;rr<4;rr++){
      int r = (lane>>4)*4 + rr;
      float v = acc[j][rr] + bv;
      ln[r][c] = f2bf((v>=0.f)? v : 0.01f*v);
    }
  }
  __syncthreads();
  // LN per row (wave w owns rows w*2, w*2+1)
  for(int ri=0; ri<2; ri++){
    int r = w*2 + ri;
    float v[12]; float s = 0.f;
    #pragma unroll
    for(int i=0;i<12;i++){ v[i] = bf2f(ln[r][lane + 64*i]); s += v[i]; }
    s = wsum(s);
    float mean = s/(float)H_;
    float pv = 0.f;
    #pragma unroll
    for(int i=0;i<12;i++){ float d = v[i]-mean; pv += d*d; }
    pv = wsum(pv);
    float rstd = rsqrtf(pv/(float)H_ + 1e-5f);
    #pragma unroll
    for(int i=0;i<12;i++){
      int c = lane + 64*i;
      ln[r][c] = f2bf((v[i]-mean)*rstd*g[c] + be[c]);
    }
  }
  __syncthreads();
  // GEMM2: out = ln @ W2^T + b2
  f32x4 o[6];
  #pragma unroll
  for(int j=0;j<6;j++) o[j] = (f32x4){0.f,0.f,0.f,0.f};
  for(int kt=0;kt<24;kt++){
    int ko = kt*32 + (lane>>4)*8;
    bhalf8 a = *(const bhalf8*)(&ln[lane&15][ko]);
    bhalf8 bb[6];
    #pragma unroll
    for(int j=0;j<6;j++){
      int row = (w*6+j)*16 + (lane&15);
      bb[j] = *(const bhalf8*)(W2_b + (size_t)row*H_ + ko);
    }
    #pragma unroll
    for(int j=0;j<6;j++) o[j] = mfma16(a, bb[j], o[j]);
  }
  #pragma unroll
  for(int j=0;j<6;j++){
    int c = (w*6+j)*16 + (lane&15);
    float bv = b2[c];
    #pragma unroll
    for(int rr=0;rr<4;rr++){
      int r = (lane>>4)*4 + rr;
      out[(size_t)(row0 + r)*H_ + c] = o[j][rr] + bv;
    }
  }
}

// ---------------- query (padded to 32 rows, bf16) ----------------
__global__ void k_query(const float* __restrict__ st, const float* __restrict__ si,
                        const float* __restrict__ rel, u16* __restrict__ query_b){
  int b = blockIdx.x; int tid = threadIdx.x;
  float a = rel[b];
  const float c = 9.210340371976184f/(float)H_;  // ln(10000)/H
  for(int t=0;t<32;t++){
    for(int h=tid;h<H_;h+=256){
      float val = 0.f;
      if(t < T_){
        float ang = (float)t * __expf(-(float)(h & ~1) * c);
        float pe  = (h&1)? __cosf(ang) : __sinf(ang);
        val = a*si[b*H_+h] + (1.f-a)*st[b*H_+h] + pe;
      }
      query_b[(size_t)b*32*H_ + t*H_ + h] = f2bf(val);
    }
  }
}

// ---------------- qh = query @ Wq^T + bq  (per b,mha; MFMA) ----------------
__global__ __launch_bounds__(512) void k_qh(const u16* __restrict__ query_b,
                                            const u16* __restrict__ Wq_b,
                                            const float* __restrict__ taBin,
                                            const float* __restrict__ iaBin,
                                            u16* __restrict__ qh_b){
  int gb = blockIdx.x; int b = gb>>1, mha = gb&1;
  int tid = threadIdx.x, lane = tid&63, w = tid>>6;
  const u16* Q  = query_b + (size_t)b*32*H_;
  const u16* Wq = Wq_b + (size_t)mha*H_*H_;
  const float* bIn = mha? iaBin : taBin;
  u16* out = qh_b + (size_t)gb*32*H_;
  f32x4 acc[2][6];
  #pragma unroll
  for(int i=0;i<2;i++)
    #pragma unroll
    for(int j=0;j<6;j++) acc[i][j] = (f32x4){0.f,0.f,0.f,0.f};
  for(int kt=0;kt<24;kt++){
    int ko = kt*32 + (lane>>4)*8;
    bhalf8 a[2];
    #pragma unroll
    for(int mt=0;mt<2;mt++)
      a[mt] = *(const bhalf8*)(Q + (size_t)(mt*16 + (lane&15))*H_ + ko);
    bhalf8 bb[6];
    #pragma unroll
    for(int j=0;j<6;j++){
      int row = (w*6+j)*16 + (lane&15);
      bb[j] = *(const bhalf8*)(Wq + (size_t)row*H_ + ko);
    }
    #pragma unroll
    for(int mt=0;mt<2;mt++)
      #pragma unroll
      for(int j=0;j<6;j++) acc[mt][j] = mfma16(a[mt], bb[j], acc[mt][j]);
  }
  #pragma unroll
  for(int mt=0;mt<2;mt++)
    #pragma unroll
    for(int j=0;j<6;j++){
      int col = (w*6+j)*16 + (lane&15);
      float bq = bIn[col];
      #pragma unroll
      for(int rr=0;rr<4;rr++){
        int row = mt*16 + (lane>>4)*4 + rr;
        out[(size_t)row*H_ + col] = f2bf(acc[mt][j][rr] + bq);
      }
    }
}

// ---------------- U = qh_h @ Wk_h (rscale folded) + bias ----------------
__global__ __launch_bounds__(512) void k_u(const u16* __restrict__ qh_b,
                                           const u16* __restrict__ WkT,
                                           const float* __restrict__ taBin,
                                           const float* __restrict__ iaBin,
                                           u16* __restrict__ U_b,
                                           float* __restrict__ bias_ws){
  int gb = blockIdx.x; int mha = gb&1;
  int tid = threadIdx.x, lane = tid&63, w = tid>>6;
  const u16* qh = qh_b + (size_t)gb*32*H_;
  const u16* Wk = WkT + (size_t)mha*H_*H_;
  u16* Up = U_b + (size_t)gb*160*H_;
  const float rscale = 0.10206207261596577f;   // 1/sqrt(96)
  for(int h=0; h<8; h++){
    int hd0 = h*HD_;
    for(int jn=0; jn<6; jn++){
      int nb = (w*6+jn)*16 + (lane&15);
      bhalf8 bb[3];
      #pragma unroll
      for(int kt=0;kt<3;kt++)
        bb[kt] = *(const bhalf8*)(Wk + (size_t)nb*H_ + hd0 + kt*32 + (lane>>4)*8);
      #pragma unroll
      for(int mt=0; mt<2; mt++){
        bhalf8 a[3];
        #pragma unroll
        for(int kt=0;kt<3;kt++){
          int trow = mt*16 + (lane&15);
          a[kt] = *(const bhalf8*)(qh + (size_t)trow*H_ + hd0 + kt*32 + (lane>>4)*8);
        }
        f32x4 acc = (f32x4){0.f,0.f,0.f,0.f};
        #pragma unroll
        for(int kt=0;kt<3;kt++) acc = mfma16(a[kt], bb[kt], acc);
        #pragma unroll
        for(int rr=0;rr<4;rr++){
          int trow = mt*16 + (lane>>4)*4 + rr;
          if(trow < T_)
            Up[(size_t)(h*T_+trow)*H_ + nb] = f2bf(acc[rr]*rscale);
        }
      }
    }
  }
  if(tid < 160){
    int h = tid/T_, t = tid%T_; int hd0 = h*HD_;
    const float* bIn = mha? iaBin : taBin;
    float p = 0.f;
    for(int d=0; d<HD_; d++)
      p += bf2f(qh[(size_t)t*H_ + hd0 + d]) * bIn[H_ + hd0 + d];
    bias_ws[gb*160 + tid] = p*rscale;
  }
}

// ---------------- scores + online softmax -> P (bf16) ----------------
__global__ __launch_bounds__(512) void k_scores(const float* __restrict__ ehs,
                                                const u16* __restrict__ U_b,
                                                const float* __restrict__ bias_ws,
                                                const int* __restrict__ smask,
                                                const int* __restrict__ imask,
                                                u16* __restrict__ P_b){
  int gb = blockIdx.x; int b = gb>>1, mha = gb&1;
  const int* msk = mha? imask : smask;
  int tid = threadIdx.x, lane = tid&63, w = tid>>6;
  __shared__ float sc[80][132];
  __shared__ float sbias[160], m_run[160], s_run[160], m_w[4][160];
  for(int r=tid; r<160; r+=512){
    sbias[r] = bias_ws[gb*160 + r];
    m_run[r] = -3e38f; s_run[r] = 0.f;
  }
  __syncthreads();
  const u16* Ub = U_b + (size_t)gb*160*H_;
  u16* Pbase = P_b + (size_t)gb*160*S_;
  int mw = w>>2, ntl = w&3;
  int arow0 = mw*80;
  for(int p=0;p<4;p++){
    f32x4 acc[5][2];
    #pragma unroll
    for(int i=0;i<5;i++)
      #pragma unroll
      for(int j=0;j<2;j++) acc[i][j] = (f32x4){0.f,0.f,0.f,0.f};
    for(int kt=0;kt<24;kt++){
      int ko = kt*32 + (lane>>4)*8;
      bhalf8 a[5];
      #pragma unroll
      for(int i=0;i<5;i++){
        int row = arow0 + i*16 + (lane&15);
        a[i] = *(const bhalf8*)(Ub + (size_t)row*H_ + ko);
      }
      bhalf8 bb[2];
      #pragma unroll
      for(int t2=0;t2<2;t2++){
        int s = p*128 + ntl*32 + t2*16 + (lane&15);
        const float* ep = ehs + ((size_t)b*S_ + s)*H_ + ko;
        float4 v0 = *(const float4*)ep;
        float4 v1 = *(const float4*)(ep+4);
        U8 u;
        u.u[0]=cvtpk(v0.x,v0.y); u.u[1]=cvtpk(v0.z,v0.w);
        u.u[2]=cvtpk(v1.x,v1.y); u.u[3]=cvtpk(v1.z,v1.w);
        bb[t2]=u.s;
      }
      #pragma unroll
      for(int i=0;i<5;i++)
        #pragma unroll
        for(int t2=0;t2<2;t2++) acc[i][t2] = mfma16(a[i], bb[t2], acc[i][t2]);
    }
    // dump + online-softmax stats, one 80-row half at a time
    for(int half=0; half<2; half++){
      __syncthreads();
      if(mw == half){
        #pragma unroll
        for(int i=0;i<5;i++)
          #pragma unroll
          for(int t2=0;t2<2;t2++)
            #pragma unroll
            for(int rr=0;rr<4;rr++){
              int rloc = i*16 + (lane>>4)*4 + rr;
              int cl = ntl*32 + t2*16 + (lane&15);
              sc[rloc][cl] = acc[i][t2][rr];
            }
      }
      __syncthreads();
      for(int ri=0; ri<10; ri++){
        int rloc = w*10 + ri;
        int row = half*80 + rloc;
        float bias = sbias[row];
        float v0 = sc[rloc][lane] + bias;
        float v1 = sc[rloc][lane+64] + bias;
        int sA = p*128 + lane, sB = sA + 64;
        bool mA = msk[b*S_ + sA] != 0;
        bool mB = msk[b*S_ + sB] != 0;
        float mx = fmaxf(mA? v0 : -3e38f, mB? v1 : -3e38f);
        mx = wmaxr(mx);
        float mo = m_run[row];
        float mn = fmaxf(mo, mx);
        float e0 = mA? __expf(v0 - mn) : 0.f;
        float e1 = mB? __expf(v1 - mn) : 0.f;
        float sum = wsum(e0 + e1);
        if(lane==0){
          s_run[row] = s_run[row]*__expf(mo - mn) + sum;
          m_run[row] = mn;
          m_w[p][row] = mn;
        }
        u16* Pp = Pbase + (size_t)row*S_;
        Pp[sA] = f2bf(e0);
        Pp[sB] = f2bf(e1);
      }
    }
  }
  __syncthreads();
  // fixup: rescale each pass-chunk to final max/sum
  for(int ri=0; ri<20; ri++){
    int row = w*20 + ri;
    float mf_ = m_run[row];
    float inv = 1.f/s_run[row];
    u16* Pp = Pbase + (size_t)row*S_;
    for(int p=0;p<4;p++){
      float f = __expf(m_w[p][row] - mf_)*inv;
      int c0 = p*128 + lane;
      float a0 = bf2f(Pp[c0])*f;
      float a1 = bf2f(Pp[c0+64])*f;
      Pp[c0]    = f2bf(a0);
      Pp[c0+64] = f2bf(a1);
    }
  }
}

// ---------------- ctx = P @ ehs (bf16 out) ----------------
__global__ __launch_bounds__(512) void k_ctx(const float* __restrict__ ehs,
                                             const u16* __restrict__ P_b,
                                             u16* __restrict__ ctx_b){
  int gb = blockIdx.x; int b = gb>>1;
  int tid = threadIdx.x, lane = tid&63, w = tid>>6;
  const u16* Pp = P_b + (size_t)gb*160*S_;
  u16* Cp = ctx_b + (size_t)gb*160*H_;
  for(int ch=0; ch<3; ch++){
    f32x4 acc[10][2];
    #pragma unroll
    for(int i=0;i<10;i++)
      #pragma unroll
      for(int j=0;j<2;j++) acc[i][j] = (f32x4){0.f,0.f,0.f,0.f};
    int n0 = ch*256 + w*32;
    for(int kt=0;kt<16;kt++){
      int ko = kt*32 + (lane>>4)*8;
      bhalf8 a[10];
      #pragma unroll
      for(int i=0;i<10;i++){
        int row = i*16 + (lane&15);
        a[i] = *(const bhalf8*)(Pp + (size_t)row*S_ + ko);
      }
      bhalf8 bb[2];
      #pragma unroll
      for(int t2=0;t2<2;t2++){
        int n = n0 + t2*16 + (lane&15);
        const float* ep = ehs + (size_t)b*S_*H_ + n;
        float v[8];
        #pragma unroll
        for(int j=0;j<8;j++) v[j] = ep[(size_t)(ko + j)*H_];
        U8 u;
        u.u[0]=cvtpk(v[0],v[1]); u.u[1]=cvtpk(v[2],v[3]);
        u.u[2]=cvtpk(v[4],v[5]); u.u[3]=cvtpk(v[6],v[7]);
        bb[t2]=u.s;
      }
      #pragma unroll
      for(int i=0;i<10;i++)
        #pragma unroll
        for(int t2=0;t2<2;t2++) acc[i][t2] = mfma16(a[i], bb[t2], acc[i][t2]);
    }
    #pragma unroll
    for(int i=0;i<10;i++)
      #pragma unroll
      for(int t2=0;t2<2;t2++){
        int col = n0 + t2*16 + (lane&15);
        #pragma unroll
        for(int rr=0;rr<4;rr++){
          int row = i*16 + (lane>>4)*4 + rr;
          Cp[(size_t)row*H_ + col] = f2bf(acc[i][t2][rr]);
        }
      }
  }
}

// ---------------- out = (ctx@Wv^T + bv) @ Wout^T  ----------------
__global__ __launch_bounds__(512) void k_out(const u16* __restrict__ ctx_b,
                                             const u16* __restrict__ Wv_b,
                                             const u16* __restrict__ Wo_b,
                                             const float* __restrict__ taBin,
                                             const float* __restrict__ iaBin,
                                             float* __restrict__ out_t,
                                             float* __restrict__ out_i){
  int gb = blockIdx.x; int b = gb>>1, mha = gb&1;
  int tid = threadIdx.x, lane = tid&63, w = tid>>6;
  const float* bIn = mha? iaBin : taBin;
  const u16* Wv = Wv_b + (size_t)mha*H_*H_;
  const u16* Wo = Wo_b + (size_t)mha*H_*H_;
  const u16* Cp = ctx_b + (size_t)gb*160*H_;
  __shared__ u16 vt[32][784];
  // GEMM5: wave w = head w
  int hd0 = w*HD_;
  {
    f32x4 acc[2][6];
    #pragma unroll
    for(int i=0;i<2;i++)
      #pragma unroll
      for(int j=0;j<6;j++) acc[i][j] = (f32x4){0.f,0.f,0.f,0.f};
    for(int kt=0;kt<24;kt++){
      int ko = kt*32 + (lane>>4)*8;
      bhalf8 a[2];
      #pragma unroll
      for(int mt=0;mt<2;mt++){
        int trow = mt*16 + (lane&15);
        a[mt] = *(const bhalf8*)(Cp + (size_t)(w*T_ + trow)*H_ + ko);
      }
      bhalf8 bb[6];
      #pragma unroll
      for(int j=0;j<6;j++){
        int row = hd0 + j*16 + (lane&15);
        bb[j] = *(const bhalf8*)(Wv + (size_t)row*H_ + ko);
      }
      #pragma unroll
      for(int mt=0;mt<2;mt++)
        #pragma unroll
        for(int j=0;j<6;j++) acc[mt][j] = mfma16(a[mt], bb[j], acc[mt][j]);
    }
    #pragma unroll
    for(int mt=0;mt<2;mt++)
      #pragma unroll
      for(int j=0;j<6;j++){
        int col = j*16 + (lane&15);
        float bv = bIn[2*H_ + hd0 + col];
        #pragma unroll
        for(int rr=0;rr<4;rr++){
          int trow = mt*16 + (lane>>4)*4 + rr;
          vt[trow][hd0 + col] = f2bf(acc[mt][j][rr] + bv);
        }
      }
  }
  __syncthreads();
  // GEMM6: out = vt @ Wo^T
  {
    f32x4 o[2][6];
    #pragma unroll
    for(int i=0;i<2;i++)
      #pragma unroll
      for(int j=0;j<6;j++) o[i][j] = (f32x4){0.f,0.f,0.f,0.f};
    for(int kt=0;kt<24;kt++){
      int ko = kt*32 + (lane>>4)*8;
      bhalf8 a[2];
      #pragma unroll
      for(int mt=0;mt<2;mt++)
        a[mt] = *(const bhalf8*)(&vt[mt*16 + (lane&15)][ko]);
      bhalf8 bb[6];
      #pragma unroll
      for(int j=0;j<6;j++){
        int row = (w*6+j)*16 + (lane&15);
        bb[j] = *(const bhalf8*)(Wo + (size_t)row*H_ + ko);
      }
      #pragma unroll
      for(int mt=0;mt<2;mt++)
        #pragma unroll
        for(int j=0;j<6;j++) o[mt][j] = mfma16(a[mt], bb[j], o[mt][j]);
    }
    float* op = (mha? out_i : out_t) + (size_t)b*T_*H_;
    #pragma unroll
    for(int mt=0;mt<2;mt++)
      #pragma unroll
      for(int j=0;j<6;j++){
        int col = (w*6+j)*16 + (lane&15);
        #pragma unroll
        for(int rr=0;rr<4;rr++){
          int trow = mt*16 + (lane>>4)*4 + rr;
          if(trow < T_) op[(size_t)trow*H_ + col] = o[mt][j][rr];
        }
      }
  }
}

// ---------------- comb = beta*(out_i+bi) + (1-beta)*(out_t+bt) (bf16) ----------------
__global__ void k_comb(const float* __restrict__ out_t, const float* __restrict__ out_i,
                       const float* __restrict__ taBout, const float* __restrict__ iaBout,
                       const float* __restrict__ rel, u16* __restrict__ comb_b){
  int bt = blockIdx.x; int b = bt/T_;
  float beta = rel[b];
  for(int h=threadIdx.x; h<H_; h+=256){
    float vt = out_t[(size_t)bt*H_+h] + taBout[h];
    float vi = out_i[(size_t)bt*H_+h] + iaBout[h];
    comb_b[(size_t)bt*H_+h] = f2bf(beta*vi + (1.f-beta)*vt);
  }
}

// ---------------- cap = relu(LN(comb @ laW^T + laB)) ----------------
__global__ __launch_bounds__(512) void k_cap2(const u16* __restrict__ comb_b,
                                              const u16* __restrict__ laW_b,
                                              const float* __restrict__ laB,
                                              const float* __restrict__ laG,
                                              const float* __restrict__ laBe,
                                              float* __restrict__ cap){
  int blk = blockIdx.x; int row0 = blk*16;
  int tid = threadIdx.x, lane = tid&63, w = tid>>6;
  __shared__ float sy[16][776];
  f32x4 acc[6];
  #pragma unroll
  for(int j=0;j<6;j++) acc[j] = (f32x4){0.f,0.f,0.f,0.f};
  for(int kt=0;kt<24;kt++){
    int ko = kt*32 + (lane>>4)*8;
    bhalf8 a = *(const bhalf8*)(comb_b + (size_t)(row0 + (lane&15))*H_ + ko);
    bhalf8 bb[6];
    #pragma unroll
    for(int j=0;j<6;j++){
      int row = (w*6+j)*16 + (lane&15);
      bb[j] = *(const bhalf8*)(laW_b + (size_t)row*H_ + ko);
    }
    #pragma unroll
    for(int j=0;j<6;j++) acc[j] = mfma16(a, bb[j], acc[j]);
  }
  #pragma unroll
  for(int j=0;j<6;j++){
    int c = (w*6+j)*16 + (lane&15);
    float lb = laB[c];
    #pragma unroll
    for(int rr=0;rr<4;rr++){
      int r = (lane>>4)*4 + rr;
      sy[r][c] = acc[j][rr] + lb;
    }
  }
  __syncthreads();
  for(int ri=0; ri<2; ri++){
    int r = w*2 + ri;
    float v[12];
    float s = 0.f;
    #pragma unroll
    for(int i=0;i<12;i++){ v[i] = sy[r][lane + 64*i]; s += v[i]; }
    s = wsum(s);
    float mean = s/(float)H_;
    float pv = 0.f;
    #pragma unroll
    for(int i=0;i<12;i++){ float d = v[i]-mean; pv += d*d; }
    pv = wsum(pv);
    float rstd = rsqrtf(pv/(float)H_ + 1e-5f);
    float* cp = cap + (size_t)(row0 + r)*H_;
    #pragma unroll
    for(int i=0;i<12;i++){
      int c = lane + 64*i;
      float o = (v[i]-mean)*rstd*laG[c] + laBe[c];
      cp[c] = (o>0.f)? o : 0.f;
    }
  }
}

// ------- fused quality head: mean over T -> MFMA GEMM -> LN -> relu -> dot -> sigmoid -------
__global__ __launch_bounds__(512) void k_quality2(const float* __restrict__ cap,
                                                  const u16* __restrict__ qW1_b,
                                                  const float* __restrict__ qB1,
                                                  const float* __restrict__ qG,
                                                  const float* __restrict__ qBe,
                                                  const float* __restrict__ qW2,
                                                  const float* __restrict__ qB2,
                                                  float* __restrict__ outq){
  const int H2 = H_/2;  // 384
  int b0 = blockIdx.x*16;
  int tid = threadIdx.x, lane = tid&63, w = tid>>6;
  __shared__ u16 sm_a[16][772];
  __shared__ float sy[16][388];
  // mean over T (coalesced: consecutive tid -> consecutive col)
  for(int e=tid; e<16*H_; e+=512){
    int r = e/H_, c = e%H_;
    const float* cp = cap + ((size_t)(b0+r)*T_)*H_ + c;
    float s = 0.f;
    #pragma unroll
    for(int t=0;t<T_;t++) s += cp[(size_t)t*H_];
    sm_a[r][c] = f2bf(s*(1.f/(float)T_));
  }
  __syncthreads();
  // GEMM1: h = m @ qW1^T   (8 waves x 3 tiles x 16 = 384 cols)
  f32x4 acc[3];
  #pragma unroll
  for(int j=0;j<3;j++) acc[j] = (f32x4){0.f,0.f,0.f,0.f};
  for(int kt=0;kt<24;kt++){
    int ko = kt*32 + (lane>>4)*8;
    bhalf8 a = *(const bhalf8*)(&sm_a[lane&15][ko]);
    bhalf8 bb[3];
    #pragma unroll
    for(int j=0;j<3;j++){
      int row = (w*3+j)*16 + (lane&15);
      bb[j] = *(const bhalf8*)(qW1_b + (size_t)row*H_ + ko);
    }
    #pragma unroll
    for(int j=0;j<3;j++) acc[j] = mfma16(a, bb[j], acc[j]);
  }
  #pragma unroll
  for(int j=0;j<3;j++){
    int c = (w*3+j)*16 + (lane&15);
    float q1 = qB1[c];
    #pragma unroll
    for(int rr=0;rr<4;rr++){
      int r = (lane>>4)*4 + rr;
      sy[r][c] = acc[j][rr] + q1;
    }
  }
  __syncthreads();
  // LN + relu + dot(qW2) + sigmoid, wave w owns rows w*2, w*2+1
  for(int ri=0; ri<2; ri++){
    int r = w*2 + ri;
    float v[6]; float s = 0.f;
    #pragma unroll
    for(int i=0;i<6;i++){ v[i] = sy[r][lane + 64*i]; s += v[i]; }
    s = wsum(s);
    float mean = s/(float)H2;
    float pv = 0.f;
    #pragma unroll
    for(int i=0;i<6;i++){ float d = v[i]-mean; pv += d*d; }
    pv = wsum(pv);
    float rstd = rsqrtf(pv/(float)H2 + 1e-5f);
    float dot = 0.f;
    #pragma unroll
    for(int i=0;i<6;i++){
      int c = lane + 64*i;
      float u = (v[i]-mean)*rstd*qG[c] + qBe[c];
      u = (u>0.f)? u : 0.f;
      dot += u*qW2[c];
    }
    dot = wsum(dot);
    if(lane==0){
      float z = dot + qB2[0];
      outq[b0+r] = 1.f/(1.f+__expf(-z));
    }
  }
}

extern "C" void kernel_launch(void* const* d_in, const int* in_sizes, int n_in,
                              void* d_out, int out_size, void* d_ws, size_t ws_size,
                              hipStream_t stream){
  const float* ehs    = (const float*)d_in[0];
  const float* rel    = (const float*)d_in[1];
  const float* tW1    = (const float*)d_in[3];
  const float* tb1    = (const float*)d_in[4];
  const float* tg     = (const float*)d_in[5];
  const float* tbe    = (const float*)d_in[6];
  const float* tW2    = (const float*)d_in[7];
  const float* tb2    = (const float*)d_in[8];
  const float* iW1    = (const float*)d_in[9];
  const float* ib1    = (const float*)d_in[10];
  const float* ig     = (const float*)d_in[11];
  const float* ibe    = (const float*)d_in[12];
  const float* iW2    = (const float*)d_in[13];
  const float* ib2    = (const float*)d_in[14];
  const float* taWin  = (const float*)d_in[15];
  const float* taBin  = (const float*)d_in[16];
  const float* taWout = (const float*)d_in[17];
  const float* taBout = (const float*)d_in[18];
  const float* iaWin  = (const float*)d_in[19];
  const float* iaBin  = (const float*)d_in[20];
  const float* iaWout = (const float*)d_in[21];
  const float* iaBout = (const float*)d_in[22];
  const float* laW    = (const float*)d_in[23];
  const float* laB    = (const float*)d_in[24];
  const float* laG    = (const float*)d_in[25];
  const float* laBe   = (const float*)d_in[26];
  const float* qW1    = (const float*)d_in[27];
  const float* qB1    = (const float*)d_in[28];
  const float* qG     = (const float*)d_in[29];
  const float* qBe    = (const float*)d_in[30];
  const float* qW2    = (const float*)d_in[31];
  const float* qB2    = (const float*)d_in[32];
  const int* smask    = (const int*)d_in[33];
  const int* imask    = (const int*)d_in[34];

  char* p = (char*)d_ws;
  auto take = [&](size_t bytes)->char*{
    char* r = p; p += (bytes + 255) & ~(size_t)255; return r;
  };
  float* st      = (float*)take((size_t)B_*H_*4);
  float* si      = (float*)take((size_t)B_*H_*4);
  u16*  pt_b     = (u16*)take((size_t)B_*H_*2);
  u16*  pi_b     = (u16*)take((size_t)B_*H_*2);
  u16*  query_b  = (u16*)take((size_t)B_*32*H_*2);
  u16*  qh_b     = (u16*)take((size_t)B_*2*32*H_*2);
  u16*  WkT      = (u16*)take((size_t)2*H_*H_*2);
  u16*  Wq_b     = (u16*)take((size_t)2*H_*H_*2);
  u16*  Wv_b     = (u16*)take((size_t)2*H_*H_*2);
  u16*  Wo_b     = (u16*)take((size_t)2*H_*H_*2);
  u16*  laW_b    = (u16*)take((size_t)H_*H_*2);
  u16*  tW1_b    = (u16*)take((size_t)H_*H_*2);
  u16*  tW2_b    = (u16*)take((size_t)H_*H_*2);
  u16*  iW1_b    = (u16*)take((size_t)H_*H_*2);
  u16*  iW2_b    = (u16*)take((size_t)H_*H_*2);
  u16*  qW1_b    = (u16*)take((size_t)(H_/2)*H_*2);
  float* bias_ws = (float*)take((size_t)B_*2*160*4);
  u16*  U_b      = (u16*)take((size_t)B_*2*160*H_*2);   // aliased by ctx_b
  u16*  P_b      = (u16*)take((size_t)B_*2*160*S_*2);
  float* out_t   = (float*)take((size_t)B_*T_*H_*4);
  float* out_i   = (float*)take((size_t)B_*T_*H_*4);
  u16*  comb_b   = (u16*)take((size_t)B_*T_*H_*2);
  u16*  ctx_b    = U_b;

  const int nW2 = (H_*H_)/2;   // pairs per 768x768 matrix
  const int cvtg = (nW2 + 255)/256;
  const int nQ2 = ((H_/2)*H_)/2;
  const int cvtgq = (nQ2 + 255)/256;

  // weight conversions
  hipLaunchKernelGGL(k_cvt, dim3(cvtg), dim3(256), 0, stream, taWin,              Wq_b,           nW2);
  hipLaunchKernelGGL(k_cvt, dim3(cvtg), dim3(256), 0, stream, iaWin,              Wq_b + (size_t)H_*H_, nW2);
  hipLaunchKernelGGL(k_cvt, dim3(cvtg), dim3(256), 0, stream, taWin + 2*H_*H_,    Wv_b,           nW2);
  hipLaunchKernelGGL(k_cvt, dim3(cvtg), dim3(256), 0, stream, iaWin + 2*H_*H_,    Wv_b + (size_t)H_*H_, nW2);
  hipLaunchKernelGGL(k_cvt, dim3(cvtg), dim3(256), 0, stream, taWout,             Wo_b,           nW2);
  hipLaunchKernelGGL(k_cvt, dim3(cvtg), dim3(256), 0, stream, iaWout,             Wo_b + (size_t)H_*H_, nW2);
  hipLaunchKernelGGL(k_cvt, dim3(cvtg), dim3(256), 0, stream, laW,                laW_b,          nW2);
  hipLaunchKernelGGL(k_cvt, dim3(cvtg), dim3(256), 0, stream, tW1,                tW1_b,          nW2);
  hipLaunchKernelGGL(k_cvt, dim3(cvtg), dim3(256), 0, stream, tW2,                tW2_b,          nW2);
  hipLaunchKernelGGL(k_cvt, dim3(cvtg), dim3(256), 0, stream, iW1,                iW1_b,          nW2);
  hipLaunchKernelGGL(k_cvt, dim3(cvtg), dim3(256), 0, stream, iW2,                iW2_b,          nW2);
  hipLaunchKernelGGL(k_cvt, dim3(cvtgq), dim3(256), 0, stream, qW1,               qW1_b,          nQ2);
  hipLaunchKernelGGL(k_wkt, dim3(1152), dim3(256), 0, stream, taWin, iaWin, WkT);

  // pooling + seeds + query
  hipLaunchKernelGGL(k_pool,  dim3(B_*3), dim3(256), 0, stream, ehs, smask, imask, pt_b, pi_b);
  hipLaunchKernelGGL(k_seed,  dim3(B_/16), dim3(512), 0, stream, pt_b, tW1_b, tb1, tg, tbe, tW2_b, tb2, st);
  hipLaunchKernelGGL(k_seed,  dim3(B_/16), dim3(512), 0, stream, pi_b, iW1_b, ib1, ig, ibe, iW2_b, ib2, si);
  hipLaunchKernelGGL(k_query, dim3(B_),   dim3(256), 0, stream, st, si, rel, query_b);

  // attention pipeline
  hipLaunchKernelGGL(k_qh,     dim3(B_*2), dim3(512), 0, stream, query_b, Wq_b, taBin, iaBin, qh_b);
  hipLaunchKernelGGL(k_u,      dim3(B_*2), dim3(512), 0, stream, qh_b, WkT, taBin, iaBin, U_b, bias_ws);
  hipLaunchKernelGGL(k_scores, dim3(B_*2), dim3(512), 0, stream, ehs, U_b, bias_ws, smask, imask, P_b);
  hipLaunchKernelGGL(k_ctx,    dim3(B_*2), dim3(512), 0, stream, ehs, P_b, ctx_b);
  hipLaunchKernelGGL(k_out,    dim3(B_*2), dim3(512), 0, stream, ctx_b, Wv_b, Wo_b, taBin, iaBin, out_t, out_i);

  // epilogue
  float* cap = (float*)d_out;
  hipLaunchKernelGGL(k_comb, dim3(B_*T_), dim3(256), 0, stream, out_t, out_i, taBout, iaBout, rel, comb_b);
  hipLaunchKernelGGL(k_cap2, dim3((B_*T_)/16), dim3(512), 0, stream, comb_b, laW_b, laB, laG, laBe, cap);
  hipLaunchKernelGGL(k_quality2, dim3(B_/16), dim3(512), 0, stream,
                     cap, qW1_b, qB1, qG, qBe, qW2, qB2, cap + (size_t)B_*T_*H_);
}